// Round 1
// baseline (6957.101 us; speedup 1.0000x reference)
//
#include <hip/hip_runtime.h>
#include <hip/hip_bf16.h>
#include <math.h>

// ---------------- degree / normalization ----------------

__global__ void deg_kernel(const int* __restrict__ col, float* __restrict__ deg, int E) {
    int e = blockIdx.x * blockDim.x + threadIdx.x;
    if (e < E) atomicAdd(&deg[col[e]], 1.0f);
}

__global__ void dinv_kernel(const float* __restrict__ deg, float* __restrict__ dinv,
                            float* __restrict__ deginv, int M) {
    int i = blockIdx.x * blockDim.x + threadIdx.x;
    if (i < M) {
        float d = deg[i] + 1.0f;   // +1 self loop
        dinv[i] = rsqrtf(d);
        deginv[i] = 1.0f / d;
    }
}

__global__ void norm_kernel(const int* __restrict__ row, const int* __restrict__ col,
                            const float* __restrict__ dinv, float* __restrict__ nrm, int E) {
    int e = blockIdx.x * blockDim.x + threadIdx.x;
    if (e < E) nrm[e] = dinv[row[e]] * dinv[col[e]];
}

// ---------------- fp32 tiled GEMM: C[M,N] = A[M,K] @ B[K,N] ----------------
// BM=BN=64, BK=16, 256 threads, 4x4 micro-tile. K,N multiples of 16/64.

#define BM 64
#define BN 64
#define BKT 16

__global__ __launch_bounds__(256) void gemm_f32(const float* __restrict__ A,
                                                const float* __restrict__ B,
                                                float* __restrict__ C,
                                                int M, int K, int N) {
    __shared__ float As[BKT][BM];
    __shared__ float Bs[BKT][BN];
    int tid = threadIdx.x;
    int row0 = blockIdx.x * BM;
    int col0 = blockIdx.y * BN;
    int tx = tid & 15;        // 0..15 -> 4 cols each
    int ty = tid >> 4;        // 0..15 -> 4 rows each

    int a_r = tid >> 2;            // 0..63
    int a_k = (tid & 3) << 2;      // 0,4,8,12
    int b_k = tid >> 4;            // 0..15
    int b_c = (tid & 15) << 2;     // 0..60

    float acc[4][4] = {};

    for (int k0 = 0; k0 < K; k0 += BKT) {
        float4 av;
        int gr = row0 + a_r;
        if (gr < M) av = *(const float4*)(A + (size_t)gr * K + k0 + a_k);
        else av = make_float4(0.f, 0.f, 0.f, 0.f);
        As[a_k + 0][a_r] = av.x;
        As[a_k + 1][a_r] = av.y;
        As[a_k + 2][a_r] = av.z;
        As[a_k + 3][a_r] = av.w;

        float4 bv = *(const float4*)(B + (size_t)(k0 + b_k) * N + col0 + b_c);
        *(float4*)&Bs[b_k][b_c] = bv;

        __syncthreads();
        #pragma unroll
        for (int kk = 0; kk < BKT; ++kk) {
            float a[4], b[4];
            #pragma unroll
            for (int i = 0; i < 4; ++i) a[i] = As[kk][ty * 4 + i];
            #pragma unroll
            for (int j = 0; j < 4; ++j) b[j] = Bs[kk][tx * 4 + j];
            #pragma unroll
            for (int i = 0; i < 4; ++i)
                #pragma unroll
                for (int j = 0; j < 4; ++j) acc[i][j] += a[i] * b[j];
        }
        __syncthreads();
    }

    #pragma unroll
    for (int i = 0; i < 4; ++i) {
        int gr = row0 + ty * 4 + i;
        if (gr < M) {
            float4 v = make_float4(acc[i][0], acc[i][1], acc[i][2], acc[i][3]);
            *(float4*)(C + (size_t)gr * N + col0 + tx * 4) = v;
        }
    }
}

// ---------------- edge scatter: dst[col] += src[row] * norm ----------------
// One wave per edge; lane owns VEC consecutive floats of the F=64*VEC row.

template <int VEC>
__global__ __launch_bounds__(256) void scatter_kernel(const int* __restrict__ row,
                                                      const int* __restrict__ col,
                                                      const float* __restrict__ nrm,
                                                      const float* __restrict__ src,
                                                      float* __restrict__ dst, int E) {
    int gtid = blockIdx.x * blockDim.x + threadIdx.x;
    int e = gtid >> 6;
    int lane = threadIdx.x & 63;
    if (e >= E) return;
    int r = row[e];
    int c = col[e];
    float w = nrm[e];
    const float* s = src + (size_t)r * (64 * VEC) + lane * VEC;
    float* d = dst + (size_t)c * (64 * VEC) + lane * VEC;
    if constexpr (VEC == 4) {
        float4 v = *(const float4*)s;
        atomicAdd(d + 0, v.x * w);
        atomicAdd(d + 1, v.y * w);
        atomicAdd(d + 2, v.z * w);
        atomicAdd(d + 3, v.w * w);
    } else {
        float2 v = *(const float2*)s;
        atomicAdd(d + 0, v.x * w);
        atomicAdd(d + 1, v.y * w);
    }
}

// ---------------- self-loop + bias + GELU (tanh approx), in place ----------------

__device__ inline float gelu_tanh(float x) {
    float x3 = x * x * x;
    return 0.5f * x * (1.0f + tanhf(0.7978845608028654f * (x + 0.044715f * x3)));
}

// h[i,k] = gelu(agg[i,k] + xw[i,k]*deginv[i] + b[k]); F=256 (64 float4/row)
__global__ void gelu_self_bias_kernel(float* __restrict__ agg, const float* __restrict__ xw,
                                      const float* __restrict__ deginv,
                                      const float* __restrict__ b, int M) {
    int idx = blockIdx.x * blockDim.x + threadIdx.x;
    if (idx >= M * 64) return;
    int i = idx >> 6;
    int k = (idx & 63) << 2;
    float di = deginv[i];
    float4 a = *(float4*)(agg + (size_t)i * 256 + k);
    float4 v = *(const float4*)(xw + (size_t)i * 256 + k);
    float4 bb = *(const float4*)(b + k);
    a.x = gelu_tanh(a.x + v.x * di + bb.x);
    a.y = gelu_tanh(a.y + v.y * di + bb.y);
    a.z = gelu_tanh(a.z + v.z * di + bb.z);
    a.w = gelu_tanh(a.w + v.w * di + bb.w);
    *(float4*)(agg + (size_t)i * 256 + k) = a;
}

// out[i,k] += xw2[i,k]*deginv[i] + b2[k]; F=128 (32 float4/row)
__global__ void final_kernel(float* __restrict__ out, const float* __restrict__ xw2,
                             const float* __restrict__ deginv,
                             const float* __restrict__ b2, int M) {
    int idx = blockIdx.x * blockDim.x + threadIdx.x;
    if (idx >= M * 32) return;
    int i = idx >> 5;
    int k = (idx & 31) << 2;
    float di = deginv[i];
    float4 o = *(float4*)(out + (size_t)i * 128 + k);
    float4 v = *(const float4*)(xw2 + (size_t)i * 128 + k);
    float4 bb = *(const float4*)(b2 + k);
    o.x += v.x * di + bb.x;
    o.y += v.y * di + bb.y;
    o.z += v.z * di + bb.z;
    o.w += v.w * di + bb.w;
    *(float4*)(out + (size_t)i * 128 + k) = o;
}

// ---------------- launch ----------------

extern "C" void kernel_launch(void* const* d_in, const int* in_sizes, int n_in,
                              void* d_out, int out_size, void* d_ws, size_t ws_size,
                              hipStream_t stream) {
    const float* x  = (const float*)d_in[0];
    const int*   ei = (const int*)d_in[1];
    const float* W1 = (const float*)d_in[2];
    const float* b1 = (const float*)d_in[3];
    const float* W2 = (const float*)d_in[4];
    const float* b2 = (const float*)d_in[5];

    const int M = in_sizes[0] / 128;      // 100000
    const int E = in_sizes[1] / 2;        // 1600000
    const int* row = ei;
    const int* col = ei + E;

    float* ws = (float*)d_ws;
    float* xw1    = ws;                      // 25,600,000 floats
    float* agg1   = xw1 + 25600000;          // 25,600,000 floats (also h after gelu)
    float* xw2    = xw1;                     // alias: xw1 dead after gelu
    float* deg    = agg1 + 25600000;         // 102,400
    float* dinv   = deg + 102400;            // 102,400
    float* dginv  = dinv + 102400;           // 102,400
    float* nrm    = dginv + 102400;          // 1,600,000
    float* outw   = (float*)d_out;

    // zero accumulators
    hipMemsetAsync(deg, 0, (size_t)M * sizeof(float), stream);
    hipMemsetAsync(agg1, 0, (size_t)M * 256 * sizeof(float), stream);
    hipMemsetAsync(d_out, 0, (size_t)M * 128 * sizeof(float), stream);

    // degree + normalization
    deg_kernel<<<(E + 255) / 256, 256, 0, stream>>>(col, deg, E);
    dinv_kernel<<<(M + 255) / 256, 256, 0, stream>>>(deg, dinv, dginv, M);
    norm_kernel<<<(E + 255) / 256, 256, 0, stream>>>(row, col, dinv, nrm, E);

    // layer 1: xw1 = x @ W1   (M x 128 @ 128 x 256)
    {
        dim3 grid((M + BM - 1) / BM, 256 / BN);
        gemm_f32<<<grid, 256, 0, stream>>>(x, W1, xw1, M, 128, 256);
    }
    // scatter: agg1[col] += xw1[row]*norm   (F=256 -> VEC=4)
    scatter_kernel<4><<<(E + 3) / 4, 256, 0, stream>>>(row, col, nrm, xw1, agg1, E);
    // h = gelu(agg1 + xw1*deginv + b1) in place
    gelu_self_bias_kernel<<<(M * 64 + 255) / 256, 256, 0, stream>>>(agg1, xw1, dginv, b1, M);

    // layer 2: xw2 = h @ W2   (M x 256 @ 256 x 128)
    {
        dim3 grid((M + BM - 1) / BM, 128 / BN);
        gemm_f32<<<grid, 256, 0, stream>>>(agg1, W2, xw2, M, 256, 128);
    }
    // scatter: out[col] += xw2[row]*norm   (F=128 -> VEC=2)
    scatter_kernel<2><<<(E + 3) / 4, 256, 0, stream>>>(row, col, nrm, xw2, outw, E);
    // out += xw2*deginv + b2
    final_kernel<<<(M * 32 + 255) / 256, 256, 0, stream>>>(outw, xw2, dginv, b2, M);
}

// Round 2
// 780.873 us; speedup vs baseline: 8.9094x; 8.9094x over previous
//
#include <hip/hip_runtime.h>
#include <hip/hip_bf16.h>
#include <math.h>

// ---------------- degree histogram (int) ----------------

__global__ void deg_kernel(const int* __restrict__ col, int* __restrict__ deg, int E) {
    int e = blockIdx.x * blockDim.x + threadIdx.x;
    if (e < E) atomicAdd(&deg[col[e]], 1);
}

__global__ void dinv_kernel(const int* __restrict__ deg, float* __restrict__ dinv,
                            float* __restrict__ deginv, int M) {
    int i = blockIdx.x * blockDim.x + threadIdx.x;
    if (i < M) {
        float d = (float)deg[i] + 1.0f;   // +1 self loop
        dinv[i] = rsqrtf(d);
        deginv[i] = 1.0f / d;
    }
}

// ---------------- hierarchical exclusive scan of deg -> off ----------------

__global__ void block_reduce_kernel(const int* __restrict__ deg, int* __restrict__ bsum, int M) {
    __shared__ int s[256];
    int i = blockIdx.x * 256 + threadIdx.x;
    s[threadIdx.x] = (i < M) ? deg[i] : 0;
    __syncthreads();
    for (int o = 128; o > 0; o >>= 1) {
        if (threadIdx.x < o) s[threadIdx.x] += s[threadIdx.x + o];
        __syncthreads();
    }
    if (threadIdx.x == 0) bsum[blockIdx.x] = s[0];
}

// single block, 512 threads, exclusive scan of nb (<=512) block sums in place
__global__ void scan_bsum_kernel(int* __restrict__ bsum, int nb) {
    __shared__ int s[512];
    int t = threadIdx.x;
    int orig = (t < nb) ? bsum[t] : 0;
    s[t] = orig;
    __syncthreads();
    for (int o = 1; o < 512; o <<= 1) {
        int v = 0;
        if (t >= o) v = s[t - o];
        __syncthreads();
        if (t >= o) s[t] += v;
        __syncthreads();
    }
    if (t < nb) bsum[t] = s[t] - orig;  // exclusive
}

__global__ void scan_offsets_kernel(const int* __restrict__ deg, const int* __restrict__ bsum,
                                    int* __restrict__ off, int M) {
    __shared__ int s[256];
    int i = blockIdx.x * 256 + threadIdx.x;
    int orig = (i < M) ? deg[i] : 0;
    s[threadIdx.x] = orig;
    __syncthreads();
    for (int o = 1; o < 256; o <<= 1) {
        int v = 0;
        if (threadIdx.x >= o) v = s[threadIdx.x - o];
        __syncthreads();
        if (threadIdx.x >= o) s[threadIdx.x] += v;
        __syncthreads();
    }
    if (i < M) off[i] = bsum[blockIdx.x] + s[threadIdx.x] - orig;  // exclusive
}

// ---------------- CSR bucket fill: rs[] = row indices grouped by col ----------------

__global__ void fill_csr_kernel(const int* __restrict__ row, const int* __restrict__ col,
                                const int* __restrict__ off, int* __restrict__ cur,
                                int* __restrict__ rs, int E) {
    int e = blockIdx.x * blockDim.x + threadIdx.x;
    if (e < E) {
        int c = col[e];
        int p = off[c] + atomicAdd(&cur[c], 1);
        rs[p] = row[e];
    }
}

// ---------------- fp32 tiled GEMM: C[M,N] = A[M,K] @ B[K,N] ----------------

#define BM 64
#define BN 64
#define BKT 16

__global__ __launch_bounds__(256) void gemm_f32(const float* __restrict__ A,
                                                const float* __restrict__ B,
                                                float* __restrict__ C,
                                                int M, int K, int N) {
    __shared__ float As[BKT][BM];
    __shared__ float Bs[BKT][BN];
    int tid = threadIdx.x;
    int row0 = blockIdx.x * BM;
    int col0 = blockIdx.y * BN;
    int tx = tid & 15;
    int ty = tid >> 4;

    int a_r = tid >> 2;
    int a_k = (tid & 3) << 2;
    int b_k = tid >> 4;
    int b_c = (tid & 15) << 2;

    float acc[4][4] = {};

    for (int k0 = 0; k0 < K; k0 += BKT) {
        float4 av;
        int gr = row0 + a_r;
        if (gr < M) av = *(const float4*)(A + (size_t)gr * K + k0 + a_k);
        else av = make_float4(0.f, 0.f, 0.f, 0.f);
        As[a_k + 0][a_r] = av.x;
        As[a_k + 1][a_r] = av.y;
        As[a_k + 2][a_r] = av.z;
        As[a_k + 3][a_r] = av.w;

        float4 bv = *(const float4*)(B + (size_t)(k0 + b_k) * N + col0 + b_c);
        *(float4*)&Bs[b_k][b_c] = bv;

        __syncthreads();
        #pragma unroll
        for (int kk = 0; kk < BKT; ++kk) {
            float a[4], b[4];
            #pragma unroll
            for (int i = 0; i < 4; ++i) a[i] = As[kk][ty * 4 + i];
            #pragma unroll
            for (int j = 0; j < 4; ++j) b[j] = Bs[kk][tx * 4 + j];
            #pragma unroll
            for (int i = 0; i < 4; ++i)
                #pragma unroll
                for (int j = 0; j < 4; ++j) acc[i][j] += a[i] * b[j];
        }
        __syncthreads();
    }

    #pragma unroll
    for (int i = 0; i < 4; ++i) {
        int gr = row0 + ty * 4 + i;
        if (gr < M) {
            float4 v = make_float4(acc[i][0], acc[i][1], acc[i][2], acc[i][3]);
            *(float4*)(C + (size_t)gr * N + col0 + tx * 4) = v;
        }
    }
}

// ---------------- fused segment-sum gathers ----------------

__device__ inline float gelu_tanh(float x) {
    float x3 = x * x * x;
    return 0.5f * x * (1.0f + tanhf(0.7978845608028654f * (x + 0.044715f * x3)));
}

// layer 1: h[i] = gelu( sum_e xw[rs]*dinv[rs]*dinv[i] + xw[i]*dginv[i] + b )
// one wave per node, F=256, lane owns float4
__global__ __launch_bounds__(256) void gather1_kernel(const int* __restrict__ off,
                                                      const int* __restrict__ deg,
                                                      const int* __restrict__ rs,
                                                      const float* __restrict__ dinv,
                                                      const float* __restrict__ dginv,
                                                      const float* __restrict__ xw,
                                                      const float* __restrict__ b,
                                                      float* __restrict__ h, int M) {
    int wid = (blockIdx.x * 256 + threadIdx.x) >> 6;
    int lane = threadIdx.x & 63;
    if (wid >= M) return;
    int s0 = off[wid];
    int n = deg[wid];
    float din = dinv[wid];
    float4 acc = make_float4(0.f, 0.f, 0.f, 0.f);
    for (int j = 0; j < n; ++j) {
        int r = rs[s0 + j];
        float w = dinv[r] * din;
        float4 v = *(const float4*)(xw + (size_t)r * 256 + lane * 4);
        acc.x += v.x * w; acc.y += v.y * w; acc.z += v.z * w; acc.w += v.w * w;
    }
    float di = dginv[wid];
    float4 sv = *(const float4*)(xw + (size_t)wid * 256 + lane * 4);
    float4 bb = *(const float4*)(b + lane * 4);
    acc.x = gelu_tanh(acc.x + sv.x * di + bb.x);
    acc.y = gelu_tanh(acc.y + sv.y * di + bb.y);
    acc.z = gelu_tanh(acc.z + sv.z * di + bb.z);
    acc.w = gelu_tanh(acc.w + sv.w * di + bb.w);
    *(float4*)(h + (size_t)wid * 256 + lane * 4) = acc;
}

// layer 2: out[i] = sum_e xw2[rs]*dinv[rs]*dinv[i] + xw2[i]*dginv[i] + b2
// one wave per node, F=128, lane owns float2
__global__ __launch_bounds__(256) void gather2_kernel(const int* __restrict__ off,
                                                      const int* __restrict__ deg,
                                                      const int* __restrict__ rs,
                                                      const float* __restrict__ dinv,
                                                      const float* __restrict__ dginv,
                                                      const float* __restrict__ xw,
                                                      const float* __restrict__ b,
                                                      float* __restrict__ out, int M) {
    int wid = (blockIdx.x * 256 + threadIdx.x) >> 6;
    int lane = threadIdx.x & 63;
    if (wid >= M) return;
    int s0 = off[wid];
    int n = deg[wid];
    float din = dinv[wid];
    float2 acc = make_float2(0.f, 0.f);
    for (int j = 0; j < n; ++j) {
        int r = rs[s0 + j];
        float w = dinv[r] * din;
        float2 v = *(const float2*)(xw + (size_t)r * 128 + lane * 2);
        acc.x += v.x * w; acc.y += v.y * w;
    }
    float di = dginv[wid];
    float2 sv = *(const float2*)(xw + (size_t)wid * 128 + lane * 2);
    float2 bb = *(const float2*)(b + lane * 2);
    acc.x += sv.x * di + bb.x;
    acc.y += sv.y * di + bb.y;
    *(float2*)(out + (size_t)wid * 128 + lane * 2) = acc;
}

// ---------------- launch ----------------

extern "C" void kernel_launch(void* const* d_in, const int* in_sizes, int n_in,
                              void* d_out, int out_size, void* d_ws, size_t ws_size,
                              hipStream_t stream) {
    const float* x  = (const float*)d_in[0];
    const int*   ei = (const int*)d_in[1];
    const float* W1 = (const float*)d_in[2];
    const float* b1 = (const float*)d_in[3];
    const float* W2 = (const float*)d_in[4];
    const float* b2 = (const float*)d_in[5];

    const int M = in_sizes[0] / 128;      // 100000
    const int E = in_sizes[1] / 2;        // 1600000
    const int* row = ei;
    const int* col = ei + E;

    float* ws = (float*)d_ws;
    float* xw1   = ws;                      // 25,600,000 f
    float* h     = xw1 + 25600000;          // 25,600,000 f
    float* xw2   = xw1;                     // alias: xw1 dead after gather1
    float* dinv  = h + 25600000;            // 102,400 f
    float* dginv = dinv + 102400;           // 102,400 f
    int*   deg   = (int*)(dginv + 102400);  // 102,400 i
    int*   off   = deg + 102400;            // 102,400 i
    int*   cur   = off + 102400;            // 102,400 i
    int*   rs    = cur + 102400;            // 1,600,000 i
    int*   bsum  = rs + 1600000;            // 1,024 i
    float* outw  = (float*)d_out;

    const int nb = (M + 255) / 256;         // 391 blocks

    hipMemsetAsync(deg, 0, (size_t)M * sizeof(int), stream);
    hipMemsetAsync(cur, 0, (size_t)M * sizeof(int), stream);

    // degree + inverse norms
    deg_kernel<<<(E + 255) / 256, 256, 0, stream>>>(col, deg, E);
    dinv_kernel<<<(M + 255) / 256, 256, 0, stream>>>(deg, dinv, dginv, M);

    // exclusive scan deg -> off
    block_reduce_kernel<<<nb, 256, 0, stream>>>(deg, bsum, M);
    scan_bsum_kernel<<<1, 512, 0, stream>>>(bsum, nb);
    scan_offsets_kernel<<<nb, 256, 0, stream>>>(deg, bsum, off, M);

    // bucket fill (CSR by destination)
    fill_csr_kernel<<<(E + 255) / 256, 256, 0, stream>>>(row, col, off, cur, rs, E);

    // layer 1
    {
        dim3 grid((M + BM - 1) / BM, 256 / BN);
        gemm_f32<<<grid, 256, 0, stream>>>(x, W1, xw1, M, 128, 256);
    }
    gather1_kernel<<<(M * 64 + 255) / 256, 256, 0, stream>>>(off, deg, rs, dinv, dginv,
                                                             xw1, b1, h, M);
    // layer 2
    {
        dim3 grid((M + BM - 1) / BM, 128 / BN);
        gemm_f32<<<grid, 256, 0, stream>>>(h, W2, xw2, M, 256, 128);
    }
    gather2_kernel<<<(M * 64 + 255) / 256, 256, 0, stream>>>(off, deg, rs, dinv, dginv,
                                                             xw2, b2, outw, M);
}

// Round 3
// 707.607 us; speedup vs baseline: 9.8319x; 1.1035x over previous
//
#include <hip/hip_runtime.h>
#include <hip/hip_bf16.h>
#include <math.h>

// ---------------- degree histogram (int) ----------------

__global__ void deg_kernel(const int* __restrict__ col, int* __restrict__ deg, int E) {
    int e = blockIdx.x * blockDim.x + threadIdx.x;
    if (e < E) atomicAdd(&deg[col[e]], 1);
}

__global__ void dinv_kernel(const int* __restrict__ deg, float* __restrict__ dinv,
                            float* __restrict__ deginv, int M) {
    int i = blockIdx.x * blockDim.x + threadIdx.x;
    if (i < M) {
        float d = (float)deg[i] + 1.0f;   // +1 self loop
        dinv[i] = rsqrtf(d);
        deginv[i] = 1.0f / d;
    }
}

// ---------------- hierarchical exclusive scan of deg -> off ----------------

__global__ void block_reduce_kernel(const int* __restrict__ deg, int* __restrict__ bsum, int M) {
    __shared__ int s[256];
    int i = blockIdx.x * 256 + threadIdx.x;
    s[threadIdx.x] = (i < M) ? deg[i] : 0;
    __syncthreads();
    for (int o = 128; o > 0; o >>= 1) {
        if (threadIdx.x < o) s[threadIdx.x] += s[threadIdx.x + o];
        __syncthreads();
    }
    if (threadIdx.x == 0) bsum[blockIdx.x] = s[0];
}

// single block, 512 threads, exclusive scan of nb (<=512) block sums in place
__global__ void scan_bsum_kernel(int* __restrict__ bsum, int nb) {
    __shared__ int s[512];
    int t = threadIdx.x;
    int orig = (t < nb) ? bsum[t] : 0;
    s[t] = orig;
    __syncthreads();
    for (int o = 1; o < 512; o <<= 1) {
        int v = 0;
        if (t >= o) v = s[t - o];
        __syncthreads();
        if (t >= o) s[t] += v;
        __syncthreads();
    }
    if (t < nb) bsum[t] = s[t] - orig;  // exclusive
}

__global__ void scan_offsets_kernel(const int* __restrict__ deg, const int* __restrict__ bsum,
                                    int* __restrict__ off, int M) {
    __shared__ int s[256];
    int i = blockIdx.x * 256 + threadIdx.x;
    int orig = (i < M) ? deg[i] : 0;
    s[threadIdx.x] = orig;
    __syncthreads();
    for (int o = 1; o < 256; o <<= 1) {
        int v = 0;
        if (threadIdx.x >= o) v = s[threadIdx.x - o];
        __syncthreads();
        if (threadIdx.x >= o) s[threadIdx.x] += v;
        __syncthreads();
    }
    if (i < M) off[i] = bsum[blockIdx.x] + s[threadIdx.x] - orig;  // exclusive
}

// ---------------- CSR bucket fill: rs[] = row indices grouped by col ----------------

__global__ void fill_csr_kernel(const int* __restrict__ row, const int* __restrict__ col,
                                const int* __restrict__ off, int* __restrict__ cur,
                                int* __restrict__ rs, int E) {
    int e = blockIdx.x * blockDim.x + threadIdx.x;
    if (e < E) {
        int c = col[e];
        int p = off[c] + atomicAdd(&cur[c], 1);
        rs[p] = row[e];
    }
}

// ---------------- fp32 tiled GEMM: C[M,N] = (opt gelu)(A[M,K] @ B[K,N] + bias) ----------------

#define BM 64
#define BN 64
#define BKT 16

__device__ inline float gelu_tanh(float x) {
    float x3 = x * x * x;
    return 0.5f * x * (1.0f + tanhf(0.7978845608028654f * (x + 0.044715f * x3)));
}

template <bool GELU_BIAS>
__global__ __launch_bounds__(256) void gemm_f32(const float* __restrict__ A,
                                                const float* __restrict__ B,
                                                const float* __restrict__ bias,
                                                float* __restrict__ C,
                                                int M, int K, int N) {
    __shared__ float As[BKT][BM];
    __shared__ float Bs[BKT][BN];
    int tid = threadIdx.x;
    int row0 = blockIdx.x * BM;
    int col0 = blockIdx.y * BN;
    int tx = tid & 15;
    int ty = tid >> 4;

    int a_r = tid >> 2;
    int a_k = (tid & 3) << 2;
    int b_k = tid >> 4;
    int b_c = (tid & 15) << 2;

    float acc[4][4] = {};

    for (int k0 = 0; k0 < K; k0 += BKT) {
        float4 av;
        int gr = row0 + a_r;
        if (gr < M) av = *(const float4*)(A + (size_t)gr * K + k0 + a_k);
        else av = make_float4(0.f, 0.f, 0.f, 0.f);
        As[a_k + 0][a_r] = av.x;
        As[a_k + 1][a_r] = av.y;
        As[a_k + 2][a_r] = av.z;
        As[a_k + 3][a_r] = av.w;

        float4 bv = *(const float4*)(B + (size_t)(k0 + b_k) * N + col0 + b_c);
        *(float4*)&Bs[b_k][b_c] = bv;

        __syncthreads();
        #pragma unroll
        for (int kk = 0; kk < BKT; ++kk) {
            float a[4], b[4];
            #pragma unroll
            for (int i = 0; i < 4; ++i) a[i] = As[kk][ty * 4 + i];
            #pragma unroll
            for (int j = 0; j < 4; ++j) b[j] = Bs[kk][tx * 4 + j];
            #pragma unroll
            for (int i = 0; i < 4; ++i)
                #pragma unroll
                for (int j = 0; j < 4; ++j) acc[i][j] += a[i] * b[j];
        }
        __syncthreads();
    }

    float4 bb;
    if constexpr (GELU_BIAS) bb = *(const float4*)(bias + col0 + tx * 4);

    #pragma unroll
    for (int i = 0; i < 4; ++i) {
        int gr = row0 + ty * 4 + i;
        if (gr < M) {
            float4 v = make_float4(acc[i][0], acc[i][1], acc[i][2], acc[i][3]);
            if constexpr (GELU_BIAS) {
                v.x = gelu_tanh(v.x + bb.x);
                v.y = gelu_tanh(v.y + bb.y);
                v.z = gelu_tanh(v.z + bb.z);
                v.w = gelu_tanh(v.w + bb.w);
            }
            *(float4*)(C + (size_t)gr * N + col0 + tx * 4) = v;
        }
    }
}

// ---------------- segment-sum gathers over F=128 (one wave/node, float2/lane) ----------------

// aggx[i] = sum_j x[rs_j]*dinv[rs_j]*dinv[i] + x[i]*dginv[i]
__global__ __launch_bounds__(256) void gatherx_kernel(const int* __restrict__ off,
                                                      const int* __restrict__ deg,
                                                      const int* __restrict__ rs,
                                                      const float* __restrict__ dinv,
                                                      const float* __restrict__ dginv,
                                                      const float* __restrict__ x,
                                                      float* __restrict__ aggx, int M) {
    int wid = (blockIdx.x * 256 + threadIdx.x) >> 6;
    int lane = threadIdx.x & 63;
    if (wid >= M) return;
    int s0 = off[wid];
    int n = deg[wid];
    float din = dinv[wid];
    float2 acc = make_float2(0.f, 0.f);
    for (int j = 0; j < n; ++j) {
        int r = rs[s0 + j];
        float w = dinv[r] * din;
        float2 v = *(const float2*)(x + (size_t)r * 128 + lane * 2);
        acc.x += v.x * w; acc.y += v.y * w;
    }
    float di = dginv[wid];
    float2 sv = *(const float2*)(x + (size_t)wid * 128 + lane * 2);
    acc.x += sv.x * di;
    acc.y += sv.y * di;
    *(float2*)(aggx + (size_t)wid * 128 + lane * 2) = acc;
}

// out[i] = sum_j xw[rs_j]*dinv[rs_j]*dinv[i] + xw[i]*dginv[i] + b
__global__ __launch_bounds__(256) void gatherout_kernel(const int* __restrict__ off,
                                                        const int* __restrict__ deg,
                                                        const int* __restrict__ rs,
                                                        const float* __restrict__ dinv,
                                                        const float* __restrict__ dginv,
                                                        const float* __restrict__ xw,
                                                        const float* __restrict__ b,
                                                        float* __restrict__ out, int M) {
    int wid = (blockIdx.x * 256 + threadIdx.x) >> 6;
    int lane = threadIdx.x & 63;
    if (wid >= M) return;
    int s0 = off[wid];
    int n = deg[wid];
    float din = dinv[wid];
    float2 acc = make_float2(0.f, 0.f);
    for (int j = 0; j < n; ++j) {
        int r = rs[s0 + j];
        float w = dinv[r] * din;
        float2 v = *(const float2*)(xw + (size_t)r * 128 + lane * 2);
        acc.x += v.x * w; acc.y += v.y * w;
    }
    float di = dginv[wid];
    float2 sv = *(const float2*)(xw + (size_t)wid * 128 + lane * 2);
    float2 bb = *(const float2*)(b + lane * 2);
    acc.x += sv.x * di + bb.x;
    acc.y += sv.y * di + bb.y;
    *(float2*)(out + (size_t)wid * 128 + lane * 2) = acc;
}

// ---------------- launch ----------------

extern "C" void kernel_launch(void* const* d_in, const int* in_sizes, int n_in,
                              void* d_out, int out_size, void* d_ws, size_t ws_size,
                              hipStream_t stream) {
    const float* x  = (const float*)d_in[0];
    const int*   ei = (const int*)d_in[1];
    const float* W1 = (const float*)d_in[2];
    const float* b1 = (const float*)d_in[3];
    const float* W2 = (const float*)d_in[4];
    const float* b2 = (const float*)d_in[5];

    const int M = in_sizes[0] / 128;      // 100000
    const int E = in_sizes[1] / 2;        // 1600000
    const int* row = ei;
    const int* col = ei + E;

    float* ws = (float*)d_ws;
    float* aggx  = ws;                      // 12,800,000 f [N,128]
    float* h     = aggx + 12800000;         // 25,600,000 f [N,256]
    float* xw2   = aggx;                    // alias: aggx dead after gemm1
    float* dinv  = h + 25600000;            // 102,400 f
    float* dginv = dinv + 102400;           // 102,400 f
    int*   deg   = (int*)(dginv + 102400);  // 102,400 i
    int*   off   = deg + 102400;            // 102,400 i
    int*   cur   = off + 102400;            // 102,400 i
    int*   rs    = cur + 102400;            // 1,600,000 i
    int*   bsum  = rs + 1600000;            // 1,024 i
    float* outw  = (float*)d_out;

    const int nb = (M + 255) / 256;         // 391 blocks

    hipMemsetAsync(deg, 0, (size_t)M * sizeof(int), stream);
    hipMemsetAsync(cur, 0, (size_t)M * sizeof(int), stream);

    // degree + inverse norms
    deg_kernel<<<(E + 255) / 256, 256, 0, stream>>>(col, deg, E);
    dinv_kernel<<<(M + 255) / 256, 256, 0, stream>>>(deg, dinv, dginv, M);

    // exclusive scan deg -> off
    block_reduce_kernel<<<nb, 256, 0, stream>>>(deg, bsum, M);
    scan_bsum_kernel<<<1, 512, 0, stream>>>(bsum, nb);
    scan_offsets_kernel<<<nb, 256, 0, stream>>>(deg, bsum, off, M);

    // bucket fill (CSR by destination)
    fill_csr_kernel<<<(E + 255) / 256, 256, 0, stream>>>(row, col, off, cur, rs, E);

    // layer 1: aggregate first (F=128), then GEMM with fused bias+gelu
    gatherx_kernel<<<(M * 64 + 255) / 256, 256, 0, stream>>>(off, deg, rs, dinv, dginv,
                                                             x, aggx, M);
    {
        dim3 grid((M + BM - 1) / BM, 256 / BN);
        gemm_f32<true><<<grid, 256, 0, stream>>>(aggx, W1, b1, h, M, 128, 256);
    }

    // layer 2: GEMM first (256->128), then aggregate + self-loop + bias
    {
        dim3 grid((M + BM - 1) / BM, 128 / BN);
        gemm_f32<false><<<grid, 256, 0, stream>>>(h, W2, nullptr, xw2, M, 256, 128);
    }
    gatherout_kernel<<<(M * 64 + 255) / 256, 256, 0, stream>>>(off, deg, rs, dinv, dginv,
                                                               xw2, b2, outw, M);
}

// Round 4
// 607.761 us; speedup vs baseline: 11.4471x; 1.1643x over previous
//
#include <hip/hip_runtime.h>
#include <hip/hip_bf16.h>
#include <math.h>

// ---------------- degree histogram (int) ----------------

__global__ void deg_kernel(const int* __restrict__ col, int* __restrict__ deg, int E) {
    int e = blockIdx.x * blockDim.x + threadIdx.x;
    if (e < E) atomicAdd(&deg[col[e]], 1);
}

__global__ void dinv_kernel(const int* __restrict__ deg, float* __restrict__ dinv,
                            float* __restrict__ deginv, int M) {
    int i = blockIdx.x * blockDim.x + threadIdx.x;
    if (i < M) {
        float d = (float)deg[i] + 1.0f;   // +1 self loop
        dinv[i] = rsqrtf(d);
        deginv[i] = 1.0f / d;
    }
}

// ---------------- hierarchical exclusive scan of deg -> off ----------------

__global__ void block_reduce_kernel(const int* __restrict__ deg, int* __restrict__ bsum, int M) {
    __shared__ int s[256];
    int i = blockIdx.x * 256 + threadIdx.x;
    s[threadIdx.x] = (i < M) ? deg[i] : 0;
    __syncthreads();
    for (int o = 128; o > 0; o >>= 1) {
        if (threadIdx.x < o) s[threadIdx.x] += s[threadIdx.x + o];
        __syncthreads();
    }
    if (threadIdx.x == 0) bsum[blockIdx.x] = s[0];
}

__global__ void scan_bsum_kernel(int* __restrict__ bsum, int nb) {
    __shared__ int s[512];
    int t = threadIdx.x;
    int orig = (t < nb) ? bsum[t] : 0;
    s[t] = orig;
    __syncthreads();
    for (int o = 1; o < 512; o <<= 1) {
        int v = 0;
        if (t >= o) v = s[t - o];
        __syncthreads();
        if (t >= o) s[t] += v;
        __syncthreads();
    }
    if (t < nb) bsum[t] = s[t] - orig;  // exclusive
}

__global__ void scan_offsets_kernel(const int* __restrict__ deg, const int* __restrict__ bsum,
                                    int* __restrict__ off, int M) {
    __shared__ int s[256];
    int i = blockIdx.x * 256 + threadIdx.x;
    int orig = (i < M) ? deg[i] : 0;
    s[threadIdx.x] = orig;
    __syncthreads();
    for (int o = 1; o < 256; o <<= 1) {
        int v = 0;
        if (threadIdx.x >= o) v = s[threadIdx.x - o];
        __syncthreads();
        if (threadIdx.x >= o) s[threadIdx.x] += v;
        __syncthreads();
    }
    if (i < M) off[i] = bsum[blockIdx.x] + s[threadIdx.x] - orig;  // exclusive
}

// ---------------- CSR bucket fill ----------------

__global__ void fill_csr_kernel(const int* __restrict__ row, const int* __restrict__ col,
                                const int* __restrict__ off, int* __restrict__ cur,
                                int* __restrict__ rs, int E) {
    int e = blockIdx.x * blockDim.x + threadIdx.x;
    if (e < E) {
        int c = col[e];
        int p = off[c] + atomicAdd(&cur[c], 1);
        rs[p] = row[e];
    }
}

// ---------------- fp32 tiled GEMM: C = (opt gelu)(A@B + bias) ----------------
// BM=128, BN=64, BK=16, 256 threads, 8x4 micro-tile.

#define BM 128
#define BN 64
#define BKT 16

__device__ inline float gelu_tanh(float x) {
    float x3 = x * x * x;
    return 0.5f * x * (1.0f + tanhf(0.7978845608028654f * (x + 0.044715f * x3)));
}

template <bool GELU_BIAS>
__global__ __launch_bounds__(256) void gemm_f32(const float* __restrict__ A,
                                                const float* __restrict__ B,
                                                const float* __restrict__ bias,
                                                float* __restrict__ C,
                                                int M, int K, int N) {
    __shared__ float As[BKT][BM];
    __shared__ float Bs[BKT][BN];
    int tid = threadIdx.x;
    int row0 = blockIdx.x * BM;
    int col0 = blockIdx.y * BN;
    int tx = tid & 15;        // 16 x 4 cols
    int ty = tid >> 4;        // 16 x 8 rows

    int a_r = tid >> 2;            // 0..63
    int a_k = (tid & 3) << 2;      // 0,4,8,12
    int b_k = tid >> 4;            // 0..15
    int b_c = (tid & 15) << 2;     // 0..60

    float acc[8][4] = {};

    for (int k0 = 0; k0 < K; k0 += BKT) {
        float4 av0 = make_float4(0.f, 0.f, 0.f, 0.f);
        float4 av1 = make_float4(0.f, 0.f, 0.f, 0.f);
        int gr0 = row0 + a_r;
        int gr1 = row0 + a_r + 64;
        if (gr0 < M) av0 = *(const float4*)(A + (size_t)gr0 * K + k0 + a_k);
        if (gr1 < M) av1 = *(const float4*)(A + (size_t)gr1 * K + k0 + a_k);
        As[a_k + 0][a_r] = av0.x;
        As[a_k + 1][a_r] = av0.y;
        As[a_k + 2][a_r] = av0.z;
        As[a_k + 3][a_r] = av0.w;
        As[a_k + 0][a_r + 64] = av1.x;
        As[a_k + 1][a_r + 64] = av1.y;
        As[a_k + 2][a_r + 64] = av1.z;
        As[a_k + 3][a_r + 64] = av1.w;

        float4 bv = *(const float4*)(B + (size_t)(k0 + b_k) * N + col0 + b_c);
        *(float4*)&Bs[b_k][b_c] = bv;

        __syncthreads();
        #pragma unroll
        for (int kk = 0; kk < BKT; ++kk) {
            float a[8], b[4];
            #pragma unroll
            for (int i = 0; i < 8; ++i) a[i] = As[kk][ty * 8 + i];
            #pragma unroll
            for (int j = 0; j < 4; ++j) b[j] = Bs[kk][tx * 4 + j];
            #pragma unroll
            for (int i = 0; i < 8; ++i)
                #pragma unroll
                for (int j = 0; j < 4; ++j) acc[i][j] += a[i] * b[j];
        }
        __syncthreads();
    }

    float4 bb;
    if constexpr (GELU_BIAS) bb = *(const float4*)(bias + col0 + tx * 4);

    #pragma unroll
    for (int i = 0; i < 8; ++i) {
        int gr = row0 + ty * 8 + i;
        if (gr < M) {
            float4 v = make_float4(acc[i][0], acc[i][1], acc[i][2], acc[i][3]);
            if constexpr (GELU_BIAS) {
                v.x = gelu_tanh(v.x + bb.x);
                v.y = gelu_tanh(v.y + bb.y);
                v.z = gelu_tanh(v.z + bb.z);
                v.w = gelu_tanh(v.w + bb.w);
            }
            *(float4*)(C + (size_t)gr * N + col0 + tx * 4) = v;
        }
    }
}

// ---------------- segment-sum gather, F=128 ----------------
// One wave per node. Lanes 0-31 process edge j (float4/lane = full 512B row),
// lanes 32-63 process edge j+1. Next edge-index pair prefetched one iter ahead.
// BIAS_SELF: add bias (gatherout); else plain self term only (gatherx).

template <bool BIAS>
__global__ __launch_bounds__(256) void gather_kernel(const int* __restrict__ off,
                                                     const int* __restrict__ deg,
                                                     const int* __restrict__ rs,
                                                     const float* __restrict__ dinv,
                                                     const float* __restrict__ dginv,
                                                     const float* __restrict__ src,
                                                     const float* __restrict__ b,
                                                     float* __restrict__ dst, int M) {
    int wid = (blockIdx.x * 256 + threadIdx.x) >> 6;
    int lane = threadIdx.x & 63;
    int half = lane >> 5;     // 0: even edge, 1: odd edge
    int l32 = lane & 31;
    if (wid >= M) return;
    int s0 = off[wid];
    int n = deg[wid];
    float din = dinv[wid];
    float4 acc = make_float4(0.f, 0.f, 0.f, 0.f);

    int npair = n & ~1;
    int r_next = 0;
    if (npair > 0) r_next = rs[s0 + half];
    for (int j = 0; j < npair; j += 2) {
        int r = r_next;
        if (j + 2 < npair) r_next = rs[s0 + j + 2 + half];
        float w = dinv[r] * din;
        float4 v = *(const float4*)(src + (size_t)r * 128 + (l32 << 2));
        acc.x += v.x * w; acc.y += v.y * w; acc.z += v.z * w; acc.w += v.w * w;
    }
    if (n & 1) {
        if (half == 0) {
            int r = rs[s0 + n - 1];
            float w = dinv[r] * din;
            float4 v = *(const float4*)(src + (size_t)r * 128 + (l32 << 2));
            acc.x += v.x * w; acc.y += v.y * w; acc.z += v.z * w; acc.w += v.w * w;
        }
    }
    // combine the two halves (feature f lives in lane f/4 and lane 32+f/4)
    acc.x += __shfl_xor(acc.x, 32);
    acc.y += __shfl_xor(acc.y, 32);
    acc.z += __shfl_xor(acc.z, 32);
    acc.w += __shfl_xor(acc.w, 32);

    if (half == 0) {
        float di = dginv[wid];
        float4 sv = *(const float4*)(src + (size_t)wid * 128 + (l32 << 2));
        acc.x += sv.x * di;
        acc.y += sv.y * di;
        acc.z += sv.z * di;
        acc.w += sv.w * di;
        if constexpr (BIAS) {
            float4 bb = *(const float4*)(b + (l32 << 2));
            acc.x += bb.x; acc.y += bb.y; acc.z += bb.z; acc.w += bb.w;
        }
        *(float4*)(dst + (size_t)wid * 128 + (l32 << 2)) = acc;
    }
}

// ---------------- launch ----------------

extern "C" void kernel_launch(void* const* d_in, const int* in_sizes, int n_in,
                              void* d_out, int out_size, void* d_ws, size_t ws_size,
                              hipStream_t stream) {
    const float* x  = (const float*)d_in[0];
    const int*   ei = (const int*)d_in[1];
    const float* W1 = (const float*)d_in[2];
    const float* b1 = (const float*)d_in[3];
    const float* W2 = (const float*)d_in[4];
    const float* b2 = (const float*)d_in[5];

    const int M = in_sizes[0] / 128;      // 100000
    const int E = in_sizes[1] / 2;        // 1600000
    const int* row = ei;
    const int* col = ei + E;

    float* ws = (float*)d_ws;
    float* aggx  = ws;                      // 12,800,000 f [N,128]
    float* h     = aggx + 12800000;         // 25,600,000 f [N,256]
    float* xw2   = aggx;                    // alias: aggx dead after gemm1
    float* dinv  = h + 25600000;            // 102,400 f
    float* dginv = dinv + 102400;           // 102,400 f
    int*   deg   = (int*)(dginv + 102400);  // 102,400 i
    int*   off   = deg + 102400;            // 102,400 i
    int*   cur   = off + 102400;            // 102,400 i
    int*   rs    = cur + 102400;            // 1,600,000 i
    int*   bsum  = rs + 1600000;            // 1,024 i
    float* outw  = (float*)d_out;

    const int nb = (M + 255) / 256;

    hipMemsetAsync(deg, 0, (size_t)M * sizeof(int), stream);
    hipMemsetAsync(cur, 0, (size_t)M * sizeof(int), stream);

    deg_kernel<<<(E + 255) / 256, 256, 0, stream>>>(col, deg, E);
    dinv_kernel<<<(M + 255) / 256, 256, 0, stream>>>(deg, dinv, dginv, M);

    block_reduce_kernel<<<nb, 256, 0, stream>>>(deg, bsum, M);
    scan_bsum_kernel<<<1, 512, 0, stream>>>(bsum, nb);
    scan_offsets_kernel<<<nb, 256, 0, stream>>>(deg, bsum, off, M);

    fill_csr_kernel<<<(E + 255) / 256, 256, 0, stream>>>(row, col, off, cur, rs, E);

    // layer 1: aggregate x (F=128), then GEMM with fused bias+gelu
    gather_kernel<false><<<(M * 64 + 255) / 256, 256, 0, stream>>>(off, deg, rs, dinv, dginv,
                                                                   x, nullptr, aggx, M);
    {
        dim3 grid((M + BM - 1) / BM, 256 / BN);
        gemm_f32<true><<<grid, 256, 0, stream>>>(aggx, W1, b1, h, M, 128, 256);
    }

    // layer 2: GEMM first (256->128), then aggregate + self + bias
    {
        dim3 grid((M + BM - 1) / BM, 128 / BN);
        gemm_f32<false><<<grid, 256, 0, stream>>>(h, W2, nullptr, xw2, M, 256, 128);
    }
    gather_kernel<true><<<(M * 64 + 255) / 256, 256, 0, stream>>>(off, deg, rs, dinv, dginv,
                                                                  xw2, b2, outw, M);
}

// Round 5
// 560.279 us; speedup vs baseline: 12.4172x; 1.0847x over previous
//
#include <hip/hip_runtime.h>
#include <hip/hip_bf16.h>
#include <math.h>

typedef __attribute__((ext_vector_type(8))) short bf16x8;
typedef __attribute__((ext_vector_type(4))) float f32x4;

__device__ inline ushort f2bf(float f) {
    uint u = __float_as_uint(f);
    uint r = u + 0x7fffu + ((u >> 16) & 1u);
    return (ushort)(r >> 16);
}
__device__ inline float bf2f(ushort h) { return __uint_as_float(((uint)h) << 16); }

__device__ inline float gelu_tanh(float x) {
    float x3 = x * x * x;
    return 0.5f * x * (1.0f + tanhf(0.7978845608028654f * (x + 0.044715f * x3)));
}

// ---------------- degree histogram (int) ----------------

__global__ void deg_kernel(const int* __restrict__ col, int* __restrict__ deg, int E) {
    int e = blockIdx.x * blockDim.x + threadIdx.x;
    if (e < E) atomicAdd(&deg[col[e]], 1);
}

__global__ void dinv_kernel(const int* __restrict__ deg, float* __restrict__ dinv,
                            float* __restrict__ deginv, int M) {
    int i = blockIdx.x * blockDim.x + threadIdx.x;
    if (i < M) {
        float d = (float)deg[i] + 1.0f;   // +1 self loop
        dinv[i] = rsqrtf(d);
        deginv[i] = 1.0f / d;
    }
}

// ---------------- hierarchical exclusive scan of deg -> off ----------------

__global__ void block_reduce_kernel(const int* __restrict__ deg, int* __restrict__ bsum, int M) {
    __shared__ int s[256];
    int i = blockIdx.x * 256 + threadIdx.x;
    s[threadIdx.x] = (i < M) ? deg[i] : 0;
    __syncthreads();
    for (int o = 128; o > 0; o >>= 1) {
        if (threadIdx.x < o) s[threadIdx.x] += s[threadIdx.x + o];
        __syncthreads();
    }
    if (threadIdx.x == 0) bsum[blockIdx.x] = s[0];
}

__global__ void scan_bsum_kernel(int* __restrict__ bsum, int nb) {
    __shared__ int s[512];
    int t = threadIdx.x;
    int orig = (t < nb) ? bsum[t] : 0;
    s[t] = orig;
    __syncthreads();
    for (int o = 1; o < 512; o <<= 1) {
        int v = 0;
        if (t >= o) v = s[t - o];
        __syncthreads();
        if (t >= o) s[t] += v;
        __syncthreads();
    }
    if (t < nb) bsum[t] = s[t] - orig;  // exclusive
}

__global__ void scan_offsets_kernel(const int* __restrict__ deg, const int* __restrict__ bsum,
                                    int* __restrict__ off, int M) {
    __shared__ int s[256];
    int i = blockIdx.x * 256 + threadIdx.x;
    int orig = (i < M) ? deg[i] : 0;
    s[threadIdx.x] = orig;
    __syncthreads();
    for (int o = 1; o < 256; o <<= 1) {
        int v = 0;
        if (threadIdx.x >= o) v = s[threadIdx.x - o];
        __syncthreads();
        if (threadIdx.x >= o) s[threadIdx.x] += v;
        __syncthreads();
    }
    if (i < M) off[i] = bsum[blockIdx.x] + s[threadIdx.x] - orig;  // exclusive
}

// ---------------- CSR bucket fill ----------------

__global__ void fill_csr_kernel(const int* __restrict__ row, const int* __restrict__ col,
                                const int* __restrict__ off, int* __restrict__ cur,
                                int* __restrict__ rs, int E) {
    int e = blockIdx.x * blockDim.x + threadIdx.x;
    if (e < E) {
        int c = col[e];
        int p = off[c] + atomicAdd(&cur[c], 1);
        rs[p] = row[e];
    }
}

// ---------------- weight prep: transpose + bf16 hi/lo split ----------------
// W1 [128x256] -> WT1 [256][128]; W2 [256x128] -> WT2 [128][256]

__global__ void prep_weights(const float* __restrict__ W1, const float* __restrict__ W2,
                             ushort* __restrict__ wt1h, ushort* __restrict__ wt1l,
                             ushort* __restrict__ wt2h, ushort* __restrict__ wt2l) {
    int idx = blockIdx.x * 256 + threadIdx.x;
    if (idx < 128 * 256) {
        int k = idx >> 8, n = idx & 255;
        float f = W1[idx];
        ushort h = f2bf(f);
        wt1h[n * 128 + k] = h;
        wt1l[n * 128 + k] = f2bf(f - bf2f(h));
    } else if (idx < 2 * 128 * 256) {
        int i2 = idx - 128 * 256;
        int k = i2 >> 7, n = i2 & 127;
        float f = W2[i2];
        ushort h = f2bf(f);
        wt2h[n * 256 + k] = h;
        wt2l[n * 256 + k] = f2bf(f - bf2f(h));
    }
}

// ---------------- split-bf16 MFMA GEMM: C[M,N] = (opt gelu)(A@W + b) ----------------
// A fp32 [M,K] staged to LDS as bf16 hi/lo (XOR-swizzled). W pre-split [N][K].
// 256 thr = 4 waves (WR x WC), wave tile 32x64, 16x16x32 MFMA, 3-product split.

template <int K, int N, int WR, int WC, bool GELU>
__global__ __launch_bounds__(256) void gemm_mfma(const float* __restrict__ A,
                                                 const ushort* __restrict__ WTh,
                                                 const ushort* __restrict__ WTl,
                                                 const float* __restrict__ bias,
                                                 float* __restrict__ C, int M) {
    constexpr int BR = WR * 32;
    __shared__ ushort lhi[BR * K];
    __shared__ ushort llo[BR * K];

    const int t = threadIdx.x;
    const int R0 = blockIdx.x * BR;

    // stage + split A tile
    constexpr int NCH = BR * K / 4;            // float4 chunks (multiple of 256)
    #pragma unroll
    for (int base = 0; base < NCH; base += 256) {
        int idx = base + t;
        int r = idx / (K / 4);
        int c4 = idx % (K / 4);
        int gr = R0 + r;
        float4 v = make_float4(0.f, 0.f, 0.f, 0.f);
        if (gr < M) v = *(const float4*)(A + (size_t)gr * K + c4 * 4);
        float f[4] = {v.x, v.y, v.z, v.w};
        ushort h4[4], l4[4];
        #pragma unroll
        for (int i = 0; i < 4; ++i) {
            ushort hb = f2bf(f[i]);
            h4[i] = hb;
            l4[i] = f2bf(f[i] - bf2f(hb));
        }
        int byte = (r * K + c4 * 4) * 2;
        byte ^= (r & 7) << 4;                   // bank swizzle (16B slot)
        *(ushort4*)((char*)lhi + byte) = make_ushort4(h4[0], h4[1], h4[2], h4[3]);
        *(ushort4*)((char*)llo + byte) = make_ushort4(l4[0], l4[1], l4[2], l4[3]);
    }
    __syncthreads();

    const int w = t >> 6, l = t & 63;
    const int r0w = (w / WC) * 32;
    const int c0w = (w % WC) * 64;
    const int lrow = l & 15;
    const int lk = l >> 4;                      // 0..3

    f32x4 acc[2][4] = {};

    #pragma unroll
    for (int ks = 0; ks < K / 32; ++ks) {
        const int kb = ks * 32 + lk * 8;
        bf16x8 ah[2], al[2], bh[4], bl[4];
        #pragma unroll
        for (int m = 0; m < 2; ++m) {
            int lr = r0w + m * 16 + lrow;
            int byte = (lr * K + kb) * 2;
            byte ^= (lr & 7) << 4;
            ah[m] = *(const bf16x8*)((const char*)lhi + byte);
            al[m] = *(const bf16x8*)((const char*)llo + byte);
        }
        #pragma unroll
        for (int n = 0; n < 4; ++n) {
            int col = c0w + n * 16 + lrow;
            bh[n] = *(const bf16x8*)&WTh[(size_t)col * K + kb];
            bl[n] = *(const bf16x8*)&WTl[(size_t)col * K + kb];
        }
        #pragma unroll
        for (int m = 0; m < 2; ++m)
            #pragma unroll
            for (int n = 0; n < 4; ++n) {
                acc[m][n] = __builtin_amdgcn_mfma_f32_16x16x32_bf16(ah[m], bh[n], acc[m][n], 0, 0, 0);
                acc[m][n] = __builtin_amdgcn_mfma_f32_16x16x32_bf16(ah[m], bl[n], acc[m][n], 0, 0, 0);
                acc[m][n] = __builtin_amdgcn_mfma_f32_16x16x32_bf16(al[m], bh[n], acc[m][n], 0, 0, 0);
            }
    }

    // epilogue: C/D layout col = l&15, row = (l>>4)*4 + reg
    #pragma unroll
    for (int m = 0; m < 2; ++m) {
        int rbase = R0 + r0w + m * 16 + lk * 4;
        #pragma unroll
        for (int n = 0; n < 4; ++n) {
            int col = c0w + n * 16 + lrow;
            float bb = 0.f;
            if constexpr (GELU) bb = bias[col];
            #pragma unroll
            for (int reg = 0; reg < 4; ++reg) {
                int row = rbase + reg;
                if (row < M) {
                    float v = acc[m][n][reg];
                    if constexpr (GELU) v = gelu_tanh(v + bb);
                    C[(size_t)row * N + col] = v;
                }
            }
        }
    }
}

// ---------------- segment-sum gather, F=128, 4 edges in flight ----------------
// One wave per node; lanes 0-31 = even edge, 32-63 = odd edge; float4/lane.

template <bool BIAS>
__global__ __launch_bounds__(256) void gather_kernel(const int* __restrict__ off,
                                                     const int* __restrict__ deg,
                                                     const int* __restrict__ rs,
                                                     const float* __restrict__ dinv,
                                                     const float* __restrict__ dginv,
                                                     const float* __restrict__ src,
                                                     const float* __restrict__ b,
                                                     float* __restrict__ dst, int M) {
    int wid = (blockIdx.x * 256 + threadIdx.x) >> 6;
    int lane = threadIdx.x & 63;
    int half = lane >> 5;
    int l32 = lane & 31;
    if (wid >= M) return;
    int s0 = off[wid];
    int n = deg[wid];
    float din = dinv[wid];
    float4 acc = make_float4(0.f, 0.f, 0.f, 0.f);
    float4 acc2 = make_float4(0.f, 0.f, 0.f, 0.f);

    int j = 0;
    for (; j + 4 <= n; j += 4) {
        int ra = rs[s0 + j + half];
        int rb = rs[s0 + j + 2 + half];
        float wa = dinv[ra] * din;
        float wb = dinv[rb] * din;
        float4 va = *(const float4*)(src + (size_t)ra * 128 + (l32 << 2));
        float4 vb = *(const float4*)(src + (size_t)rb * 128 + (l32 << 2));
        acc.x += va.x * wa; acc.y += va.y * wa; acc.z += va.z * wa; acc.w += va.w * wa;
        acc2.x += vb.x * wb; acc2.y += vb.y * wb; acc2.z += vb.z * wb; acc2.w += vb.w * wb;
    }
    if (j + 2 <= n) {
        int ra = rs[s0 + j + half];
        float wa = dinv[ra] * din;
        float4 va = *(const float4*)(src + (size_t)ra * 128 + (l32 << 2));
        acc.x += va.x * wa; acc.y += va.y * wa; acc.z += va.z * wa; acc.w += va.w * wa;
        j += 2;
    }
    if (j < n && half == 0) {
        int ra = rs[s0 + j];
        float wa = dinv[ra] * din;
        float4 va = *(const float4*)(src + (size_t)ra * 128 + (l32 << 2));
        acc.x += va.x * wa; acc.y += va.y * wa; acc.z += va.z * wa; acc.w += va.w * wa;
    }
    acc.x += acc2.x; acc.y += acc2.y; acc.z += acc2.z; acc.w += acc2.w;

    acc.x += __shfl_xor(acc.x, 32);
    acc.y += __shfl_xor(acc.y, 32);
    acc.z += __shfl_xor(acc.z, 32);
    acc.w += __shfl_xor(acc.w, 32);

    if (half == 0) {
        float di = dginv[wid];
        float4 sv = *(const float4*)(src + (size_t)wid * 128 + (l32 << 2));
        acc.x += sv.x * di;
        acc.y += sv.y * di;
        acc.z += sv.z * di;
        acc.w += sv.w * di;
        if constexpr (BIAS) {
            float4 bb = *(const float4*)(b + (l32 << 2));
            acc.x += bb.x; acc.y += bb.y; acc.z += bb.z; acc.w += bb.w;
        }
        *(float4*)(dst + (size_t)wid * 128 + (l32 << 2)) = acc;
    }
}

// ---------------- launch ----------------

extern "C" void kernel_launch(void* const* d_in, const int* in_sizes, int n_in,
                              void* d_out, int out_size, void* d_ws, size_t ws_size,
                              hipStream_t stream) {
    const float* x  = (const float*)d_in[0];
    const int*   ei = (const int*)d_in[1];
    const float* W1 = (const float*)d_in[2];
    const float* b1 = (const float*)d_in[3];
    const float* W2 = (const float*)d_in[4];
    const float* b2 = (const float*)d_in[5];

    const int M = in_sizes[0] / 128;      // 100000
    const int E = in_sizes[1] / 2;        // 1600000
    const int* row = ei;
    const int* col = ei + E;

    float* ws = (float*)d_ws;
    float* aggx  = ws;                      // 12,800,000 f [N,128]
    float* h     = aggx + 12800000;         // 25,600,000 f [N,256]
    float* xw2   = aggx;                    // alias: aggx dead after gemm1
    float* dinv  = h + 25600000;            // 102,400 f
    float* dginv = dinv + 102400;           // 102,400 f
    int*   deg   = (int*)(dginv + 102400);  // 102,400 i
    int*   off   = deg + 102400;            // 102,400 i
    int*   cur   = off + 102400;            // 102,400 i
    int*   rs    = cur + 102400;            // 1,600,000 i
    int*   bsum  = rs + 1600000;            // 1,024 i
    ushort* wt1h = (ushort*)(bsum + 1024);  // 32,768 us each
    ushort* wt1l = wt1h + 32768;
    ushort* wt2h = wt1l + 32768;
    ushort* wt2l = wt2h + 32768;
    float* outw  = (float*)d_out;

    const int nb = (M + 255) / 256;

    hipMemsetAsync(deg, 0, (size_t)M * sizeof(int), stream);
    hipMemsetAsync(cur, 0, (size_t)M * sizeof(int), stream);

    deg_kernel<<<(E + 255) / 256, 256, 0, stream>>>(col, deg, E);
    dinv_kernel<<<(M + 255) / 256, 256, 0, stream>>>(deg, dinv, dginv, M);

    block_reduce_kernel<<<nb, 256, 0, stream>>>(deg, bsum, M);
    scan_bsum_kernel<<<1, 512, 0, stream>>>(bsum, nb);
    scan_offsets_kernel<<<nb, 256, 0, stream>>>(deg, bsum, off, M);

    fill_csr_kernel<<<(E + 255) / 256, 256, 0, stream>>>(row, col, off, cur, rs, E);

    prep_weights<<<256, 256, 0, stream>>>(W1, W2, wt1h, wt1l, wt2h, wt2l);

    // layer 1: aggregate x (F=128), then MFMA GEMM 128->256 with fused bias+gelu
    gather_kernel<false><<<(M * 64 + 255) / 256, 256, 0, stream>>>(off, deg, rs, dinv, dginv,
                                                                   x, nullptr, aggx, M);
    gemm_mfma<128, 256, 1, 4, true><<<(M + 31) / 32, 256, 0, stream>>>(aggx, wt1h, wt1l,
                                                                       b1, h, M);

    // layer 2: MFMA GEMM 256->128, then aggregate + self + bias
    gemm_mfma<256, 128, 2, 2, false><<<(M + 63) / 64, 256, 0, stream>>>(h, wt2h, wt2l,
                                                                        nullptr, xw2, M);
    gather_kernel<true><<<(M * 64 + 255) / 256, 256, 0, stream>>>(off, deg, rs, dinv, dginv,
                                                                  xw2, b2, outw, M);
}

// Round 8
// 510.183 us; speedup vs baseline: 13.6365x; 1.0982x over previous
//
#include <hip/hip_runtime.h>
#include <hip/hip_bf16.h>
#include <math.h>

typedef __attribute__((ext_vector_type(8))) short bf16x8;
typedef __attribute__((ext_vector_type(4))) float f32x4;

__device__ inline ushort f2bf(float f) {
    uint u = __float_as_uint(f);
    uint r = u + 0x7fffu + ((u >> 16) & 1u);
    return (ushort)(r >> 16);
}
__device__ inline float bf2f(ushort h) { return __uint_as_float(((uint)h) << 16); }

__device__ inline float gelu_tanh(float x) {
    float x3 = x * x * x;
    return 0.5f * x * (1.0f + tanhf(0.7978845608028654f * (x + 0.044715f * x3)));
}

// ---------------- degree histogram (int) ----------------

__global__ void deg_kernel(const int* __restrict__ col, int* __restrict__ deg, int E) {
    int e = blockIdx.x * blockDim.x + threadIdx.x;
    if (e < E) atomicAdd(&deg[col[e]], 1);
}

__global__ void dinv_kernel(const int* __restrict__ deg, float* __restrict__ dinv,
                            float* __restrict__ deginv, int M) {
    int i = blockIdx.x * blockDim.x + threadIdx.x;
    if (i < M) {
        float d = (float)deg[i] + 1.0f;   // +1 self loop
        dinv[i] = rsqrtf(d);
        deginv[i] = 1.0f / d;
    }
}

// ---------------- hierarchical exclusive scan of deg -> off ----------------

__global__ void block_reduce_kernel(const int* __restrict__ deg, int* __restrict__ bsum, int M) {
    __shared__ int s[256];
    int i = blockIdx.x * 256 + threadIdx.x;
    s[threadIdx.x] = (i < M) ? deg[i] : 0;
    __syncthreads();
    for (int o = 128; o > 0; o >>= 1) {
        if (threadIdx.x < o) s[threadIdx.x] += s[threadIdx.x + o];
        __syncthreads();
    }
    if (threadIdx.x == 0) bsum[blockIdx.x] = s[0];
}

__global__ void scan_bsum_kernel(int* __restrict__ bsum, int nb) {
    __shared__ int s[512];
    int t = threadIdx.x;
    int orig = (t < nb) ? bsum[t] : 0;
    s[t] = orig;
    __syncthreads();
    for (int o = 1; o < 512; o <<= 1) {
        int v = 0;
        if (t >= o) v = s[t - o];
        __syncthreads();
        if (t >= o) s[t] += v;
        __syncthreads();
    }
    if (t < nb) bsum[t] = s[t] - orig;  // exclusive
}

__global__ void scan_offsets_kernel(const int* __restrict__ deg, const int* __restrict__ bsum,
                                    int* __restrict__ off, int M) {
    __shared__ int s[256];
    int i = blockIdx.x * 256 + threadIdx.x;
    int orig = (i < M) ? deg[i] : 0;
    s[threadIdx.x] = orig;
    __syncthreads();
    for (int o = 1; o < 256; o <<= 1) {
        int v = 0;
        if (threadIdx.x >= o) v = s[threadIdx.x - o];
        __syncthreads();
        if (threadIdx.x >= o) s[threadIdx.x] += v;
        __syncthreads();
    }
    if (i < M) off[i] = bsum[blockIdx.x] + s[threadIdx.x] - orig;  // exclusive
}

// ---------------- CSR bucket fill ----------------

__global__ void fill_csr_kernel(const int* __restrict__ row, const int* __restrict__ col,
                                const int* __restrict__ off, int* __restrict__ cur,
                                int* __restrict__ rs, int E) {
    int e = blockIdx.x * blockDim.x + threadIdx.x;
    if (e < E) {
        int c = col[e];
        int p = off[c] + atomicAdd(&cur[c], 1);
        rs[p] = row[e];
    }
}

// ---------------- weight prep: transpose + bf16 hi/lo split ----------------

__global__ void prep_weights(const float* __restrict__ W1, const float* __restrict__ W2,
                             ushort* __restrict__ wt1h, ushort* __restrict__ wt1l,
                             ushort* __restrict__ wt2h, ushort* __restrict__ wt2l) {
    int idx = blockIdx.x * 256 + threadIdx.x;
    if (idx < 128 * 256) {
        int k = idx >> 8, n = idx & 255;
        float f = W1[idx];
        ushort h = f2bf(f);
        wt1h[n * 128 + k] = h;
        wt1l[n * 128 + k] = f2bf(f - bf2f(h));
    } else if (idx < 2 * 128 * 256) {
        int i2 = idx - 128 * 256;
        int k = i2 >> 7, n = i2 & 127;
        float f = W2[i2];
        ushort h = f2bf(f);
        wt2h[n * 256 + k] = h;
        wt2l[n * 256 + k] = f2bf(f - bf2f(h));
    }
}

// ---------------- fp32 -> bf16 table conversion (8 elems / thread) ----------------

__global__ void to_bf16_kernel(const float* __restrict__ in, ushort* __restrict__ out, int n8) {
    int i = blockIdx.x * 256 + threadIdx.x;
    if (i >= n8) return;
    float4 a = *(const float4*)(in + (size_t)i * 8);
    float4 b = *(const float4*)(in + (size_t)i * 8 + 4);
    ushort4 u0 = make_ushort4(f2bf(a.x), f2bf(a.y), f2bf(a.z), f2bf(a.w));
    ushort4 u1 = make_ushort4(f2bf(b.x), f2bf(b.y), f2bf(b.z), f2bf(b.w));
    *(ushort4*)(out + (size_t)i * 8) = u0;
    *(ushort4*)(out + (size_t)i * 8 + 4) = u1;
}

// ---------------- split-bf16 MFMA GEMM: C[M,N] = (opt gelu)(A@W + b) ----------------
// A fp32 [M,K] staged to LDS as bf16 hi/lo (XOR-swizzled). W pre-split [N][K].
// 256 thr = 4 waves, wave tile 32x64, 16x16x32 MFMA, 3-product split.
// Optionally also emits C in bf16 (for the following gather).

template <int K, int N, int WR, int WC, bool GELU, bool WBF16>
__global__ __launch_bounds__(256) void gemm_mfma(const float* __restrict__ A,
                                                 const ushort* __restrict__ WTh,
                                                 const ushort* __restrict__ WTl,
                                                 const float* __restrict__ bias,
                                                 float* __restrict__ C,
                                                 ushort* __restrict__ Cb, int M) {
    constexpr int BR = WR * 32;
    __shared__ ushort lhi[BR * K];
    __shared__ ushort llo[BR * K];

    const int t = threadIdx.x;
    const int R0 = blockIdx.x * BR;

    constexpr int NCH = BR * K / 4;
    #pragma unroll
    for (int base = 0; base < NCH; base += 256) {
        int idx = base + t;
        int r = idx / (K / 4);
        int c4 = idx % (K / 4);
        int gr = R0 + r;
        float4 v = make_float4(0.f, 0.f, 0.f, 0.f);
        if (gr < M) v = *(const float4*)(A + (size_t)gr * K + c4 * 4);
        float f[4] = {v.x, v.y, v.z, v.w};
        ushort h4[4], l4[4];
        #pragma unroll
        for (int i = 0; i < 4; ++i) {
            ushort hb = f2bf(f[i]);
            h4[i] = hb;
            l4[i] = f2bf(f[i] - bf2f(hb));
        }
        int byte = (r * K + c4 * 4) * 2;
        byte ^= (r & 7) << 4;
        *(ushort4*)((char*)lhi + byte) = make_ushort4(h4[0], h4[1], h4[2], h4[3]);
        *(ushort4*)((char*)llo + byte) = make_ushort4(l4[0], l4[1], l4[2], l4[3]);
    }
    __syncthreads();

    const int w = t >> 6, l = t & 63;
    const int r0w = (w / WC) * 32;
    const int c0w = (w % WC) * 64;
    const int lrow = l & 15;
    const int lk = l >> 4;

    f32x4 acc[2][4] = {};

    #pragma unroll
    for (int ks = 0; ks < K / 32; ++ks) {
        const int kb = ks * 32 + lk * 8;
        bf16x8 ah[2], al[2], bh[4], bl[4];
        #pragma unroll
        for (int m = 0; m < 2; ++m) {
            int lr = r0w + m * 16 + lrow;
            int byte = (lr * K + kb) * 2;
            byte ^= (lr & 7) << 4;
            ah[m] = *(const bf16x8*)((const char*)lhi + byte);
            al[m] = *(const bf16x8*)((const char*)llo + byte);
        }
        #pragma unroll
        for (int n = 0; n < 4; ++n) {
            int col = c0w + n * 16 + lrow;
            bh[n] = *(const bf16x8*)&WTh[(size_t)col * K + kb];
            bl[n] = *(const bf16x8*)&WTl[(size_t)col * K + kb];
        }
        #pragma unroll
        for (int m = 0; m < 2; ++m)
            #pragma unroll
            for (int n = 0; n < 4; ++n) {
                acc[m][n] = __builtin_amdgcn_mfma_f32_16x16x32_bf16(ah[m], bh[n], acc[m][n], 0, 0, 0);
                acc[m][n] = __builtin_amdgcn_mfma_f32_16x16x32_bf16(ah[m], bl[n], acc[m][n], 0, 0, 0);
                acc[m][n] = __builtin_amdgcn_mfma_f32_16x16x32_bf16(al[m], bh[n], acc[m][n], 0, 0, 0);
            }
    }

    #pragma unroll
    for (int m = 0; m < 2; ++m) {
        int rbase = R0 + r0w + m * 16 + lk * 4;
        #pragma unroll
        for (int n = 0; n < 4; ++n) {
            int col = c0w + n * 16 + lrow;
            float bb = 0.f;
            if constexpr (GELU) bb = bias[col];
            #pragma unroll
            for (int reg = 0; reg < 4; ++reg) {
                int row = rbase + reg;
                if (row < M) {
                    float v = acc[m][n][reg];
                    if constexpr (GELU) v = gelu_tanh(v + bb);
                    C[(size_t)row * N + col] = v;
                    if constexpr (WBF16) Cb[(size_t)row * N + col] = f2bf(v);
                }
            }
        }
    }
}

// ---------------- segment-sum gather, bf16 table, F=128 ----------------
// One wave per node; 4 groups of 16 lanes, one edge per group (4 edges in
// flight). Lane covers 8 features (16B bf16 load). Self term read fp32.

template <bool BIAS>
__global__ __launch_bounds__(256) void gather_bf16_kernel(const int* __restrict__ off,
                                                          const int* __restrict__ deg,
                                                          const int* __restrict__ rs,
                                                          const float* __restrict__ dinv,
                                                          const float* __restrict__ dginv,
                                                          const ushort* __restrict__ srcb,
                                                          const float* __restrict__ srcf,
                                                          const float* __restrict__ b,
                                                          float* __restrict__ dst, int M) {
    int wid = (blockIdx.x * 256 + threadIdx.x) >> 6;
    int lane = threadIdx.x & 63;
    int grp = lane >> 4;      // 0..3: which edge of the quad
    int l16 = lane & 15;      // feature block: 8 bf16 = 16B
    if (wid >= M) return;
    int s0 = off[wid];
    int n = deg[wid];
    float din = dinv[wid];
    float acc[8] = {};

    int j = 0;
    for (; j + 4 <= n; j += 4) {
        int r = rs[s0 + j + grp];
        float w = dinv[r] * din;
        bf16x8 u = *(const bf16x8*)(srcb + (size_t)r * 128 + l16 * 8);
        #pragma unroll
        for (int i = 0; i < 8; ++i) acc[i] += bf2f((ushort)u[i]) * w;
    }
    if (j + grp < n) {
        int r = rs[s0 + j + grp];
        float w = dinv[r] * din;
        bf16x8 u = *(const bf16x8*)(srcb + (size_t)r * 128 + l16 * 8);
        #pragma unroll
        for (int i = 0; i < 8; ++i) acc[i] += bf2f((ushort)u[i]) * w;
    }

    // reduce the 4 edge-groups (features f live in lanes l16, l16+16, l16+32, l16+48)
    #pragma unroll
    for (int i = 0; i < 8; ++i) {
        acc[i] += __shfl_xor(acc[i], 16);
        acc[i] += __shfl_xor(acc[i], 32);
    }

    if (grp == 0) {
        float di = dginv[wid];
        float4 s0v = *(const float4*)(srcf + (size_t)wid * 128 + l16 * 8);
        float4 s1v = *(const float4*)(srcf + (size_t)wid * 128 + l16 * 8 + 4);
        acc[0] += s0v.x * di; acc[1] += s0v.y * di;
        acc[2] += s0v.z * di; acc[3] += s0v.w * di;
        acc[4] += s1v.x * di; acc[5] += s1v.y * di;
        acc[6] += s1v.z * di; acc[7] += s1v.w * di;
        if constexpr (BIAS) {
            float4 b0 = *(const float4*)(b + l16 * 8);
            float4 b1 = *(const float4*)(b + l16 * 8 + 4);
            acc[0] += b0.x; acc[1] += b0.y; acc[2] += b0.z; acc[3] += b0.w;
            acc[4] += b1.x; acc[5] += b1.y; acc[6] += b1.z; acc[7] += b1.w;
        }
        float4 o0 = make_float4(acc[0], acc[1], acc[2], acc[3]);
        float4 o1 = make_float4(acc[4], acc[5], acc[6], acc[7]);
        *(float4*)(dst + (size_t)wid * 128 + l16 * 8) = o0;
        *(float4*)(dst + (size_t)wid * 128 + l16 * 8 + 4) = o1;
    }
}

// ---------------- launch ----------------

extern "C" void kernel_launch(void* const* d_in, const int* in_sizes, int n_in,
                              void* d_out, int out_size, void* d_ws, size_t ws_size,
                              hipStream_t stream) {
    const float* x  = (const float*)d_in[0];
    const int*   ei = (const int*)d_in[1];
    const float* W1 = (const float*)d_in[2];
    const float* b1 = (const float*)d_in[3];
    const float* W2 = (const float*)d_in[4];
    const float* b2 = (const float*)d_in[5];

    const int M = in_sizes[0] / 128;      // 100000
    const int E = in_sizes[1] / 2;        // 1600000
    const int* row = ei;
    const int* col = ei + E;

    // Workspace high-water mark ~187.9 MB (< R1-proven 213.25 MB).
    float* ws = (float*)d_ws;
    float* aggx  = ws;                      // 12,800,000 f [N,128]
    float* h     = aggx + 12800000;         // 25,600,000 f [N,256]
    ushort* xb   = (ushort*)h;              // 12,800,000 us — ALIASES h (dead until gemm1)
    float* xw2   = aggx;                    // alias: aggx dead after gemm1
    float* dinv  = h + 25600000;            // 102,400 f
    float* dginv = dinv + 102400;           // 102,400 f
    int*   deg   = (int*)(dginv + 102400);  // 102,400 i
    int*   cur   = deg + 102400;            // 102,400 i (adjacent, padded stride!)
    int*   off   = cur + 102400;            // 102,400 i
    int*   rs    = off + 102400;            // 1,600,000 i
    int*   bsum  = rs + 1600000;            // 1,024 i
    ushort* wt1h = (ushort*)(bsum + 1024);  // 32,768 us each
    ushort* wt1l = wt1h + 32768;
    ushort* wt2h = wt1l + 32768;
    ushort* wt2l = wt2h + 32768;
    ushort* xw2b = wt2l + 32768;            // 12,800,000 us (xw2 in bf16)
    float* outw  = (float*)d_out;

    const int nb = (M + 255) / 256;

    // R5/R6 BUG WAS HERE: memset of 2*M ints left cur[97600..100000) poisoned
    // (cur sits at deg + 102400, padded stride). Zero the full padded span.
    hipMemsetAsync(deg, 0, (size_t)2 * 102400 * sizeof(int), stream);

    deg_kernel<<<(E + 255) / 256, 256, 0, stream>>>(col, deg, E);
    dinv_kernel<<<(M + 255) / 256, 256, 0, stream>>>(deg, dinv, dginv, M);

    block_reduce_kernel<<<nb, 256, 0, stream>>>(deg, bsum, M);
    scan_bsum_kernel<<<1, 512, 0, stream>>>(bsum, nb);
    scan_offsets_kernel<<<nb, 256, 0, stream>>>(deg, bsum, off, M);

    fill_csr_kernel<<<(E + 255) / 256, 256, 0, stream>>>(row, col, off, cur, rs, E);

    prep_weights<<<256, 256, 0, stream>>>(W1, W2, wt1h, wt1l, wt2h, wt2l);
    to_bf16_kernel<<<(M * 16 + 255) / 256, 256, 0, stream>>>(x, xb, M * 16);

    // layer 1: aggregate x (bf16 table), then MFMA GEMM 128->256 + bias+gelu
    gather_bf16_kernel<false><<<(M * 64 + 255) / 256, 256, 0, stream>>>(
        off, deg, rs, dinv, dginv, xb, x, nullptr, aggx, M);
    gemm_mfma<128, 256, 1, 4, true, false><<<(M + 31) / 32, 256, 0, stream>>>(
        aggx, wt1h, wt1l, b1, h, nullptr, M);

    // layer 2: MFMA GEMM 256->128 (writes fp32 + bf16), then aggregate + self + bias
    gemm_mfma<256, 128, 2, 2, false, true><<<(M + 63) / 64, 256, 0, stream>>>(
        h, wt2h, wt2l, nullptr, xw2, xw2b, M);
    gather_bf16_kernel<true><<<(M * 64 + 255) / 256, 256, 0, stream>>>(
        off, deg, rs, dinv, dginv, xw2b, xw2, b2, outw, M);
}

// Round 9
// 466.193 us; speedup vs baseline: 14.9232x; 1.0944x over previous
//
#include <hip/hip_runtime.h>
#include <hip/hip_bf16.h>
#include <math.h>

typedef __attribute__((ext_vector_type(8))) short bf16x8;
typedef __attribute__((ext_vector_type(4))) float f32x4;

__device__ inline ushort f2bf(float f) {
    uint u = __float_as_uint(f);
    uint r = u + 0x7fffu + ((u >> 16) & 1u);
    return (ushort)(r >> 16);
}
__device__ inline float bf2f(ushort h) { return __uint_as_float(((uint)h) << 16); }

__device__ inline float gelu_tanh(float x) {
    float x3 = x * x * x;
    return 0.5f * x * (1.0f + tanhf(0.7978845608028654f * (x + 0.044715f * x3)));
}

// ---------------- degree histogram (int) ----------------

__global__ void deg_kernel(const int* __restrict__ col, int* __restrict__ deg, int E) {
    int e = blockIdx.x * blockDim.x + threadIdx.x;
    if (e < E) atomicAdd(&deg[col[e]], 1);
}

__global__ void dinv_kernel(const int* __restrict__ deg, float* __restrict__ dinv,
                            float* __restrict__ deginv, int M) {
    int i = blockIdx.x * blockDim.x + threadIdx.x;
    if (i < M) {
        float d = (float)deg[i] + 1.0f;   // +1 self loop
        dinv[i] = rsqrtf(d);
        deginv[i] = 1.0f / d;
    }
}

// ---------------- hierarchical exclusive scan of deg -> off ----------------

__global__ void block_reduce_kernel(const int* __restrict__ deg, int* __restrict__ bsum, int M) {
    __shared__ int s[256];
    int i = blockIdx.x * 256 + threadIdx.x;
    s[threadIdx.x] = (i < M) ? deg[i] : 0;
    __syncthreads();
    for (int o = 128; o > 0; o >>= 1) {
        if (threadIdx.x < o) s[threadIdx.x] += s[threadIdx.x + o];
        __syncthreads();
    }
    if (threadIdx.x == 0) bsum[blockIdx.x] = s[0];
}

__global__ void scan_bsum_kernel(int* __restrict__ bsum, int nb) {
    __shared__ int s[512];
    int t = threadIdx.x;
    int orig = (t < nb) ? bsum[t] : 0;
    s[t] = orig;
    __syncthreads();
    for (int o = 1; o < 512; o <<= 1) {
        int v = 0;
        if (t >= o) v = s[t - o];
        __syncthreads();
        if (t >= o) s[t] += v;
        __syncthreads();
    }
    if (t < nb) bsum[t] = s[t] - orig;  // exclusive
}

__global__ void scan_offsets_kernel(const int* __restrict__ deg, const int* __restrict__ bsum,
                                    int* __restrict__ off, int M) {
    __shared__ int s[256];
    int i = blockIdx.x * 256 + threadIdx.x;
    int orig = (i < M) ? deg[i] : 0;
    s[threadIdx.x] = orig;
    __syncthreads();
    for (int o = 1; o < 256; o <<= 1) {
        int v = 0;
        if (threadIdx.x >= o) v = s[threadIdx.x - o];
        __syncthreads();
        if (threadIdx.x >= o) s[threadIdx.x] += v;
        __syncthreads();
    }
    if (i < M) off[i] = bsum[blockIdx.x] + s[threadIdx.x] - orig;  // exclusive
}

// ---------------- CSR bucket fill ----------------

__global__ void fill_csr_kernel(const int* __restrict__ row, const int* __restrict__ col,
                                const int* __restrict__ off, int* __restrict__ cur,
                                int* __restrict__ rs, int E) {
    int e = blockIdx.x * blockDim.x + threadIdx.x;
    if (e < E) {
        int c = col[e];
        int p = off[c] + atomicAdd(&cur[c], 1);
        rs[p] = row[e];
    }
}

// ---------------- weight prep: transpose + bf16 hi/lo split ----------------

__global__ void prep_weights(const float* __restrict__ W1, const float* __restrict__ W2,
                             ushort* __restrict__ wt1h, ushort* __restrict__ wt1l,
                             ushort* __restrict__ wt2h, ushort* __restrict__ wt2l) {
    int idx = blockIdx.x * 256 + threadIdx.x;
    if (idx < 128 * 256) {
        int k = idx >> 8, n = idx & 255;
        float f = W1[idx];
        ushort h = f2bf(f);
        wt1h[n * 128 + k] = h;
        wt1l[n * 128 + k] = f2bf(f - bf2f(h));
    } else if (idx < 2 * 128 * 256) {
        int i2 = idx - 128 * 256;
        int k = i2 >> 7, n = i2 & 127;
        float f = W2[i2];
        ushort h = f2bf(f);
        wt2h[n * 256 + k] = h;
        wt2l[n * 256 + k] = f2bf(f - bf2f(h));
    }
}

// ---------------- fp32 -> bf16 table conversion (8 elems / thread) ----------------

__global__ void to_bf16_kernel(const float* __restrict__ in, ushort* __restrict__ out, int n8) {
    int i = blockIdx.x * 256 + threadIdx.x;
    if (i >= n8) return;
    float4 a = *(const float4*)(in + (size_t)i * 8);
    float4 b = *(const float4*)(in + (size_t)i * 8 + 4);
    ushort4 u0 = make_ushort4(f2bf(a.x), f2bf(a.y), f2bf(a.z), f2bf(a.w));
    ushort4 u1 = make_ushort4(f2bf(b.x), f2bf(b.y), f2bf(b.z), f2bf(b.w));
    *(ushort4*)(out + (size_t)i * 8) = u0;
    *(ushort4*)(out + (size_t)i * 8 + 4) = u1;
}

// ---------------- bf16-A MFMA GEMM: C = (opt gelu)(A@W + b) ----------------
// A bf16 [M,K] staged to LDS (XOR-swizzled, plain copies). W pre-split hi/lo
// [N][K]. 256 thr = 4 waves, wave tile 32x64, 16x16x32 MFMA, 2 products
// (A*Wh + A*Wl). Emits fp32 C and/or bf16 Cb.

template <int K, int N, int WR, int WC, bool GELU, bool WF32, bool WBF16>
__global__ __launch_bounds__(256) void gemm_bfA(const ushort* __restrict__ A,
                                                const ushort* __restrict__ WTh,
                                                const ushort* __restrict__ WTl,
                                                const float* __restrict__ bias,
                                                float* __restrict__ C,
                                                ushort* __restrict__ Cb, int M) {
    constexpr int BR = WR * 32;
    __shared__ ushort la[BR * K];

    const int t = threadIdx.x;
    const int R0 = blockIdx.x * BR;

    constexpr int NCH = BR * K / 8;            // 16B chunks
    #pragma unroll
    for (int base = 0; base < NCH; base += 256) {
        int idx = base + t;
        int r = idx / (K / 8);
        int c8 = idx % (K / 8);
        int gr = R0 + r;
        bf16x8 v = {};
        if (gr < M) v = *(const bf16x8*)(A + (size_t)gr * K + c8 * 8);
        int byte = (r * K + c8 * 8) * 2;
        byte ^= (r & 7) << 4;
        *(bf16x8*)((char*)la + byte) = v;
    }
    __syncthreads();

    const int w = t >> 6, l = t & 63;
    const int r0w = (w / WC) * 32;
    const int c0w = (w % WC) * 64;
    const int lrow = l & 15;
    const int lk = l >> 4;

    f32x4 acc[2][4] = {};

    #pragma unroll
    for (int ks = 0; ks < K / 32; ++ks) {
        const int kb = ks * 32 + lk * 8;
        bf16x8 a[2], bh[4], bl[4];
        #pragma unroll
        for (int m = 0; m < 2; ++m) {
            int lr = r0w + m * 16 + lrow;
            int byte = (lr * K + kb) * 2;
            byte ^= (lr & 7) << 4;
            a[m] = *(const bf16x8*)((const char*)la + byte);
        }
        #pragma unroll
        for (int n = 0; n < 4; ++n) {
            int col = c0w + n * 16 + lrow;
            bh[n] = *(const bf16x8*)&WTh[(size_t)col * K + kb];
            bl[n] = *(const bf16x8*)&WTl[(size_t)col * K + kb];
        }
        #pragma unroll
        for (int m = 0; m < 2; ++m)
            #pragma unroll
            for (int n = 0; n < 4; ++n) {
                acc[m][n] = __builtin_amdgcn_mfma_f32_16x16x32_bf16(a[m], bh[n], acc[m][n], 0, 0, 0);
                acc[m][n] = __builtin_amdgcn_mfma_f32_16x16x32_bf16(a[m], bl[n], acc[m][n], 0, 0, 0);
            }
    }

    #pragma unroll
    for (int m = 0; m < 2; ++m) {
        int rbase = R0 + r0w + m * 16 + lk * 4;
        #pragma unroll
        for (int n = 0; n < 4; ++n) {
            int col = c0w + n * 16 + lrow;
            float bb = 0.f;
            if constexpr (GELU) bb = bias[col];
            #pragma unroll
            for (int reg = 0; reg < 4; ++reg) {
                int row = rbase + reg;
                if (row < M) {
                    float v = acc[m][n][reg];
                    if constexpr (GELU) v = gelu_tanh(v + bb);
                    if constexpr (WF32) C[(size_t)row * N + col] = v;
                    if constexpr (WBF16) Cb[(size_t)row * N + col] = f2bf(v);
                }
            }
        }
    }
}

// ---------------- segment-sum gather, bf16 table, F=128 ----------------
// One wave per node; 4 groups of 16 lanes, one edge per group. Lane covers
// 8 features (16B bf16 load). Self term read fp32. Output fp32 or bf16.

template <bool BIAS, bool OUTBF>
__global__ __launch_bounds__(256) void gather_bf16_kernel(const int* __restrict__ off,
                                                          const int* __restrict__ deg,
                                                          const int* __restrict__ rs,
                                                          const float* __restrict__ dinv,
                                                          const float* __restrict__ dginv,
                                                          const ushort* __restrict__ srcb,
                                                          const float* __restrict__ srcf,
                                                          const float* __restrict__ b,
                                                          float* __restrict__ dstf,
                                                          ushort* __restrict__ dstb, int M) {
    int wid = (blockIdx.x * 256 + threadIdx.x) >> 6;
    int lane = threadIdx.x & 63;
    int grp = lane >> 4;      // 0..3: which edge of the quad
    int l16 = lane & 15;      // feature block: 8 bf16 = 16B
    if (wid >= M) return;
    int s0 = off[wid];
    int n = deg[wid];
    float din = dinv[wid];
    float acc[8] = {};

    int j = 0;
    for (; j + 4 <= n; j += 4) {
        int r = rs[s0 + j + grp];
        float w = dinv[r] * din;
        bf16x8 u = *(const bf16x8*)(srcb + (size_t)r * 128 + l16 * 8);
        #pragma unroll
        for (int i = 0; i < 8; ++i) acc[i] += bf2f((ushort)u[i]) * w;
    }
    if (j + grp < n) {
        int r = rs[s0 + j + grp];
        float w = dinv[r] * din;
        bf16x8 u = *(const bf16x8*)(srcb + (size_t)r * 128 + l16 * 8);
        #pragma unroll
        for (int i = 0; i < 8; ++i) acc[i] += bf2f((ushort)u[i]) * w;
    }

    #pragma unroll
    for (int i = 0; i < 8; ++i) {
        acc[i] += __shfl_xor(acc[i], 16);
        acc[i] += __shfl_xor(acc[i], 32);
    }

    if (grp == 0) {
        float di = dginv[wid];
        float4 s0v = *(const float4*)(srcf + (size_t)wid * 128 + l16 * 8);
        float4 s1v = *(const float4*)(srcf + (size_t)wid * 128 + l16 * 8 + 4);
        acc[0] += s0v.x * di; acc[1] += s0v.y * di;
        acc[2] += s0v.z * di; acc[3] += s0v.w * di;
        acc[4] += s1v.x * di; acc[5] += s1v.y * di;
        acc[6] += s1v.z * di; acc[7] += s1v.w * di;
        if constexpr (BIAS) {
            float4 b0 = *(const float4*)(b + l16 * 8);
            float4 b1 = *(const float4*)(b + l16 * 8 + 4);
            acc[0] += b0.x; acc[1] += b0.y; acc[2] += b0.z; acc[3] += b0.w;
            acc[4] += b1.x; acc[5] += b1.y; acc[6] += b1.z; acc[7] += b1.w;
        }
        if constexpr (OUTBF) {
            bf16x8 o;
            #pragma unroll
            for (int i = 0; i < 8; ++i) o[i] = (short)f2bf(acc[i]);
            *(bf16x8*)(dstb + (size_t)wid * 128 + l16 * 8) = o;
        } else {
            float4 o0 = make_float4(acc[0], acc[1], acc[2], acc[3]);
            float4 o1 = make_float4(acc[4], acc[5], acc[6], acc[7]);
            *(float4*)(dstf + (size_t)wid * 128 + l16 * 8) = o0;
            *(float4*)(dstf + (size_t)wid * 128 + l16 * 8 + 4) = o1;
        }
    }
}

// ---------------- launch ----------------

extern "C" void kernel_launch(void* const* d_in, const int* in_sizes, int n_in,
                              void* d_out, int out_size, void* d_ws, size_t ws_size,
                              hipStream_t stream) {
    const float* x  = (const float*)d_in[0];
    const int*   ei = (const int*)d_in[1];
    const float* W1 = (const float*)d_in[2];
    const float* b1 = (const float*)d_in[3];
    const float* W2 = (const float*)d_in[4];
    const float* b2 = (const float*)d_in[5];

    const int M = in_sizes[0] / 128;      // 100000
    const int E = in_sizes[1] / 2;        // 1600000
    const int* row = ei;
    const int* col = ei + E;

    // bf16 activation pipeline. High-water ~143 MB.
    ushort* hb    = (ushort*)d_ws;            // 25,600,000 us [N,256] (h bf16)
    ushort* xb    = hb;                       // 12,800,000 us — ALIASES hb front (dead before gemm1)
    ushort* aggxb = hb + 25600000;            // 12,800,000 us [N,128] (agg x bf16)
    ushort* xw2b  = aggxb;                    // alias: aggxb dead after gemm1
    float*  xw2   = (float*)(aggxb + 12800000); // 12,800,000 f [N,128]
    float*  dinv  = xw2 + 12800000;           // 102,400 f
    float*  dginv = dinv + 102400;            // 102,400 f
    int*    deg   = (int*)(dginv + 102400);   // 102,400 i
    int*    cur   = deg + 102400;             // 102,400 i (padded stride!)
    int*    off   = cur + 102400;             // 102,400 i
    int*    rs    = off + 102400;             // 1,600,000 i
    int*    bsum  = rs + 1600000;             // 1,024 i
    ushort* wt1h  = (ushort*)(bsum + 1024);   // 32,768 us each
    ushort* wt1l  = wt1h + 32768;
    ushort* wt2h  = wt1l + 32768;
    ushort* wt2l  = wt2h + 32768;
    float*  outw  = (float*)d_out;

    const int nb = (M + 255) / 256;

    // zero the FULL padded span deg+cur (R5/R6 lesson: partial memset left
    // poisoned cur entries -> OOB scatter -> page fault)
    hipMemsetAsync(deg, 0, (size_t)2 * 102400 * sizeof(int), stream);

    deg_kernel<<<(E + 255) / 256, 256, 0, stream>>>(col, deg, E);
    dinv_kernel<<<(M + 255) / 256, 256, 0, stream>>>(deg, dinv, dginv, M);

    block_reduce_kernel<<<nb, 256, 0, stream>>>(deg, bsum, M);
    scan_bsum_kernel<<<1, 512, 0, stream>>>(bsum, nb);
    scan_offsets_kernel<<<nb, 256, 0, stream>>>(deg, bsum, off, M);

    fill_csr_kernel<<<(E + 255) / 256, 256, 0, stream>>>(row, col, off, cur, rs, E);

    prep_weights<<<256, 256, 0, stream>>>(W1, W2, wt1h, wt1l, wt2h, wt2l);
    to_bf16_kernel<<<(M * 16 + 255) / 256, 256, 0, stream>>>(x, xb, M * 16);

    // layer 1: aggregate x (bf16 in, bf16 out), then bf16-A MFMA GEMM 128->256
    gather_bf16_kernel<false, true><<<(M * 64 + 255) / 256, 256, 0, stream>>>(
        off, deg, rs, dinv, dginv, xb, x, nullptr, nullptr, aggxb, M);
    gemm_bfA<128, 256, 1, 4, true, false, true><<<(M + 31) / 32, 256, 0, stream>>>(
        aggxb, wt1h, wt1l, b1, nullptr, hb, M);

    // layer 2: bf16-A MFMA GEMM 256->128 (fp32 + bf16 out), then aggregate
    gemm_bfA<256, 128, 2, 2, false, true, true><<<(M + 63) / 64, 256, 0, stream>>>(
        hb, wt2h, wt2l, nullptr, xw2, xw2b, M);
    gather_bf16_kernel<true, false><<<(M * 64 + 255) / 256, 256, 0, stream>>>(
        off, deg, rs, dinv, dginv, xw2b, xw2, b2, outw, nullptr, M);
}

// Round 10
// 412.169 us; speedup vs baseline: 16.8792x; 1.1311x over previous
//
#include <hip/hip_runtime.h>
#include <hip/hip_bf16.h>
#include <math.h>

typedef __attribute__((ext_vector_type(8))) short bf16x8;
typedef __attribute__((ext_vector_type(4))) float f32x4;

__device__ inline ushort f2bf(float f) {
    uint u = __float_as_uint(f);
    uint r = u + 0x7fffu + ((u >> 16) & 1u);
    return (ushort)(r >> 16);
}
__device__ inline float bf2f(ushort h) { return __uint_as_float(((uint)h) << 16); }

__device__ inline float gelu_tanh(float x) {
    float x3 = x * x * x;
    return 0.5f * x * (1.0f + tanhf(0.7978845608028654f * (x + 0.044715f * x3)));
}

// ---------------- pass A: degree histogram + per-edge rank ----------------

__global__ void deg_rank_kernel(const int* __restrict__ col, int* __restrict__ deg,
                                int* __restrict__ rank, int E) {
    int e = blockIdx.x * blockDim.x + threadIdx.x;
    if (e < E) rank[e] = atomicAdd(&deg[col[e]], 1);
}

__global__ void dinv_kernel(const int* __restrict__ deg, float* __restrict__ dinv,
                            float* __restrict__ deginv, int M) {
    int i = blockIdx.x * blockDim.x + threadIdx.x;
    if (i < M) {
        float d = (float)deg[i] + 1.0f;   // +1 self loop
        dinv[i] = rsqrtf(d);
        deginv[i] = 1.0f / d;
    }
}

// ---------------- hierarchical exclusive scan of deg -> off ----------------

__global__ void block_reduce_kernel(const int* __restrict__ deg, int* __restrict__ bsum, int M) {
    __shared__ int s[256];
    int i = blockIdx.x * 256 + threadIdx.x;
    s[threadIdx.x] = (i < M) ? deg[i] : 0;
    __syncthreads();
    for (int o = 128; o > 0; o >>= 1) {
        if (threadIdx.x < o) s[threadIdx.x] += s[threadIdx.x + o];
        __syncthreads();
    }
    if (threadIdx.x == 0) bsum[blockIdx.x] = s[0];
}

__global__ void scan_bsum_kernel(int* __restrict__ bsum, int nb) {
    __shared__ int s[512];
    int t = threadIdx.x;
    int orig = (t < nb) ? bsum[t] : 0;
    s[t] = orig;
    __syncthreads();
    for (int o = 1; o < 512; o <<= 1) {
        int v = 0;
        if (t >= o) v = s[t - o];
        __syncthreads();
        if (t >= o) s[t] += v;
        __syncthreads();
    }
    if (t < nb) bsum[t] = s[t] - orig;  // exclusive
}

__global__ void scan_offsets_kernel(const int* __restrict__ deg, const int* __restrict__ bsum,
                                    int* __restrict__ off, int M) {
    __shared__ int s[256];
    int i = blockIdx.x * 256 + threadIdx.x;
    int orig = (i < M) ? deg[i] : 0;
    s[threadIdx.x] = orig;
    __syncthreads();
    for (int o = 1; o < 256; o <<= 1) {
        int v = 0;
        if (threadIdx.x >= o) v = s[threadIdx.x - o];
        __syncthreads();
        if (threadIdx.x >= o) s[threadIdx.x] += v;
        __syncthreads();
    }
    if (i < M) off[i] = bsum[blockIdx.x] + s[threadIdx.x] - orig;  // exclusive
}

// ---------------- pass B: atomic-free CSR scatter ----------------

__global__ void fill_sorted_kernel(const int* __restrict__ row, const int* __restrict__ col,
                                   const int* __restrict__ off, const int* __restrict__ rank,
                                   int* __restrict__ rs, int E) {
    int e = blockIdx.x * blockDim.x + threadIdx.x;
    if (e < E) rs[off[col[e]] + rank[e]] = row[e];
}

// ---------------- weight prep: transpose + bf16 hi/lo split ----------------

__global__ void prep_weights(const float* __restrict__ W1, const float* __restrict__ W2,
                             ushort* __restrict__ wt1h, ushort* __restrict__ wt1l,
                             ushort* __restrict__ wt2h, ushort* __restrict__ wt2l) {
    int idx = blockIdx.x * 256 + threadIdx.x;
    if (idx < 128 * 256) {
        int k = idx >> 8, n = idx & 255;
        float f = W1[idx];
        ushort h = f2bf(f);
        wt1h[n * 128 + k] = h;
        wt1l[n * 128 + k] = f2bf(f - bf2f(h));
    } else if (idx < 2 * 128 * 256) {
        int i2 = idx - 128 * 256;
        int k = i2 >> 7, n = i2 & 127;
        float f = W2[i2];
        ushort h = f2bf(f);
        wt2h[n * 256 + k] = h;
        wt2l[n * 256 + k] = f2bf(f - bf2f(h));
    }
}

// ---------------- x -> bf16 table scaled by dinv[node] (8 elems/thread) ----------------

__global__ void to_bf16_scaled_kernel(const float* __restrict__ in, const float* __restrict__ dinv,
                                      ushort* __restrict__ out, int n8) {
    int i = blockIdx.x * 256 + threadIdx.x;
    if (i >= n8) return;
    float s = dinv[i >> 4];               // 16 chunks of 8 per 128-wide row
    float4 a = *(const float4*)(in + (size_t)i * 8);
    float4 b = *(const float4*)(in + (size_t)i * 8 + 4);
    ushort4 u0 = make_ushort4(f2bf(a.x * s), f2bf(a.y * s), f2bf(a.z * s), f2bf(a.w * s));
    ushort4 u1 = make_ushort4(f2bf(b.x * s), f2bf(b.y * s), f2bf(b.z * s), f2bf(b.w * s));
    *(ushort4*)(out + (size_t)i * 8) = u0;
    *(ushort4*)(out + (size_t)i * 8 + 4) = u1;
}

// ---------------- bf16-A MFMA GEMM: C = (opt gelu)(A@W + b) ----------------
// A bf16 [M,K] staged to LDS (XOR-swizzled). W pre-split hi/lo [N][K].
// 256 thr = 4 waves, wave tile 32x64, 16x16x32 MFMA, 2 products.
// Emits fp32 C and/or bf16 Cb (optionally scaled by dscale[row]).

template <int K, int N, int WR, int WC, bool GELU, bool WF32, bool WBF16, bool SCALEB>
__global__ __launch_bounds__(256) void gemm_bfA(const ushort* __restrict__ A,
                                                const ushort* __restrict__ WTh,
                                                const ushort* __restrict__ WTl,
                                                const float* __restrict__ bias,
                                                const float* __restrict__ dscale,
                                                float* __restrict__ C,
                                                ushort* __restrict__ Cb, int M) {
    constexpr int BR = WR * 32;
    __shared__ ushort la[BR * K];

    const int t = threadIdx.x;
    const int R0 = blockIdx.x * BR;

    constexpr int NCH = BR * K / 8;            // 16B chunks
    #pragma unroll
    for (int base = 0; base < NCH; base += 256) {
        int idx = base + t;
        int r = idx / (K / 8);
        int c8 = idx % (K / 8);
        int gr = R0 + r;
        bf16x8 v = {};
        if (gr < M) v = *(const bf16x8*)(A + (size_t)gr * K + c8 * 8);
        int byte = (r * K + c8 * 8) * 2;
        byte ^= (r & 7) << 4;
        *(bf16x8*)((char*)la + byte) = v;
    }
    __syncthreads();

    const int w = t >> 6, l = t & 63;
    const int r0w = (w / WC) * 32;
    const int c0w = (w % WC) * 64;
    const int lrow = l & 15;
    const int lk = l >> 4;

    f32x4 acc[2][4] = {};

    #pragma unroll
    for (int ks = 0; ks < K / 32; ++ks) {
        const int kb = ks * 32 + lk * 8;
        bf16x8 a[2], bh[4], bl[4];
        #pragma unroll
        for (int m = 0; m < 2; ++m) {
            int lr = r0w + m * 16 + lrow;
            int byte = (lr * K + kb) * 2;
            byte ^= (lr & 7) << 4;
            a[m] = *(const bf16x8*)((const char*)la + byte);
        }
        #pragma unroll
        for (int n = 0; n < 4; ++n) {
            int col = c0w + n * 16 + lrow;
            bh[n] = *(const bf16x8*)&WTh[(size_t)col * K + kb];
            bl[n] = *(const bf16x8*)&WTl[(size_t)col * K + kb];
        }
        #pragma unroll
        for (int m = 0; m < 2; ++m)
            #pragma unroll
            for (int n = 0; n < 4; ++n) {
                acc[m][n] = __builtin_amdgcn_mfma_f32_16x16x32_bf16(a[m], bh[n], acc[m][n], 0, 0, 0);
                acc[m][n] = __builtin_amdgcn_mfma_f32_16x16x32_bf16(a[m], bl[n], acc[m][n], 0, 0, 0);
            }
    }

    #pragma unroll
    for (int m = 0; m < 2; ++m) {
        int rbase = R0 + r0w + m * 16 + lk * 4;
        #pragma unroll
        for (int n = 0; n < 4; ++n) {
            int col = c0w + n * 16 + lrow;
            float bb = 0.f;
            if constexpr (GELU) bb = bias[col];
            #pragma unroll
            for (int reg = 0; reg < 4; ++reg) {
                int row = rbase + reg;
                if (row < M) {
                    float v = acc[m][n][reg];
                    if constexpr (GELU) v = gelu_tanh(v + bb);
                    if constexpr (WF32) C[(size_t)row * N + col] = v;
                    if constexpr (WBF16) {
                        float vb = v;
                        if constexpr (SCALEB) vb *= dscale[row];
                        Cb[(size_t)row * N + col] = f2bf(vb);
                    }
                }
            }
        }
    }
}

// ---------------- segment-sum gather over pre-scaled bf16 table, F=128 ----------------
// One wave per node; 4 groups of 16 lanes, one edge per group. Lane covers
// 8 features (16B bf16 load). acc = dinv[i]*sum(rows) + self*dginv (+bias).

template <bool BIAS, bool OUTBF>
__global__ __launch_bounds__(256) void gather_sum_kernel(const int* __restrict__ off,
                                                         const int* __restrict__ deg,
                                                         const int* __restrict__ rs,
                                                         const float* __restrict__ dinv,
                                                         const float* __restrict__ dginv,
                                                         const ushort* __restrict__ srcb,
                                                         const float* __restrict__ srcf,
                                                         const float* __restrict__ b,
                                                         float* __restrict__ dstf,
                                                         ushort* __restrict__ dstb, int M) {
    int wid = (blockIdx.x * 256 + threadIdx.x) >> 6;
    int lane = threadIdx.x & 63;
    int grp = lane >> 4;      // 0..3: which edge of the quad
    int l16 = lane & 15;      // feature block: 8 bf16 = 16B
    if (wid >= M) return;
    int s0 = off[wid];
    int n = deg[wid];
    float acc[8] = {};

    int j = 0;
    for (; j + 4 <= n; j += 4) {
        int r = rs[s0 + j + grp];
        bf16x8 u = *(const bf16x8*)(srcb + (size_t)r * 128 + l16 * 8);
        #pragma unroll
        for (int i = 0; i < 8; ++i) acc[i] += bf2f((ushort)u[i]);
    }
    if (j + grp < n) {
        int r = rs[s0 + j + grp];
        bf16x8 u = *(const bf16x8*)(srcb + (size_t)r * 128 + l16 * 8);
        #pragma unroll
        for (int i = 0; i < 8; ++i) acc[i] += bf2f((ushort)u[i]);
    }

    #pragma unroll
    for (int i = 0; i < 8; ++i) {
        acc[i] += __shfl_xor(acc[i], 16);
        acc[i] += __shfl_xor(acc[i], 32);
    }

    if (grp == 0) {
        float sc = dinv[wid];
        float di = dginv[wid];
        float4 s0v = *(const float4*)(srcf + (size_t)wid * 128 + l16 * 8);
        float4 s1v = *(const float4*)(srcf + (size_t)wid * 128 + l16 * 8 + 4);
        acc[0] = acc[0] * sc + s0v.x * di; acc[1] = acc[1] * sc + s0v.y * di;
        acc[2] = acc[2] * sc + s0v.z * di; acc[3] = acc[3] * sc + s0v.w * di;
        acc[4] = acc[4] * sc + s1v.x * di; acc[5] = acc[5] * sc + s1v.y * di;
        acc[6] = acc[6] * sc + s1v.z * di; acc[7] = acc[7] * sc + s1v.w * di;
        if constexpr (BIAS) {
            float4 b0 = *(const float4*)(b + l16 * 8);
            float4 b1 = *(const float4*)(b + l16 * 8 + 4);
            acc[0] += b0.x; acc[1] += b0.y; acc[2] += b0.z; acc[3] += b0.w;
            acc[4] += b1.x; acc[5] += b1.y; acc[6] += b1.z; acc[7] += b1.w;
        }
        if constexpr (OUTBF) {
            bf16x8 o;
            #pragma unroll
            for (int i = 0; i < 8; ++i) o[i] = (short)f2bf(acc[i]);
            *(bf16x8*)(dstb + (size_t)wid * 128 + l16 * 8) = o;
        } else {
            float4 o0 = make_float4(acc[0], acc[1], acc[2], acc[3]);
            float4 o1 = make_float4(acc[4], acc[5], acc[6], acc[7]);
            *(float4*)(dstf + (size_t)wid * 128 + l16 * 8) = o0;
            *(float4*)(dstf + (size_t)wid * 128 + l16 * 8 + 4) = o1;
        }
    }
}

// ---------------- launch ----------------

extern "C" void kernel_launch(void* const* d_in, const int* in_sizes, int n_in,
                              void* d_out, int out_size, void* d_ws, size_t ws_size,
                              hipStream_t stream) {
    const float* x  = (const float*)d_in[0];
    const int*   ei = (const int*)d_in[1];
    const float* W1 = (const float*)d_in[2];
    const float* b1 = (const float*)d_in[3];
    const float* W2 = (const float*)d_in[4];
    const float* b2 = (const float*)d_in[5];

    const int M = in_sizes[0] / 128;      // 100000
    const int E = in_sizes[1] / 2;        // 1600000
    const int* row = ei;
    const int* col = ei + E;

    // High-water ~149 MB (< R1-proven 213.25 MB).
    ushort* hb    = (ushort*)d_ws;              // 25,600,000 us [N,256] (h bf16)
    ushort* xb    = hb;                         // ALIASES hb front (dead before gemm1 writes)
    ushort* aggxb = hb + 25600000;              // 12,800,000 us [N,128]
    ushort* xw2b  = aggxb;                      // alias: aggxb dead after gemm1
    float*  xw2   = (float*)(aggxb + 12800000); // 12,800,000 f [N,128]
    float*  dinv  = xw2 + 12800000;             // 102,400 f
    float*  dginv = dinv + 102400;              // 102,400 f
    int*    deg   = (int*)(dginv + 102400);     // 102,400 i  (memset full padded span!)
    int*    off   = deg + 102400;               // 102,400 i
    int*    rank  = off + 102400;               // 1,600,000 i
    int*    rs    = rank + 1600000;             // 1,600,000 i
    int*    bsum  = rs + 1600000;               // 1,024 i
    ushort* wt1h  = (ushort*)(bsum + 1024);     // 32,768 us each
    ushort* wt1l  = wt1h + 32768;
    ushort* wt2h  = wt1l + 32768;
    ushort* wt2l  = wt2h + 32768;
    float*  outw  = (float*)d_out;

    const int nb = (M + 255) / 256;

    hipMemsetAsync(deg, 0, (size_t)102400 * sizeof(int), stream);  // full padded span

    // pass A: histogram + rank (one atomic pass total)
    deg_rank_kernel<<<(E + 255) / 256, 256, 0, stream>>>(col, deg, rank, E);
    dinv_kernel<<<(M + 255) / 256, 256, 0, stream>>>(deg, dinv, dginv, M);

    block_reduce_kernel<<<nb, 256, 0, stream>>>(deg, bsum, M);
    scan_bsum_kernel<<<1, 512, 0, stream>>>(bsum, nb);
    scan_offsets_kernel<<<nb, 256, 0, stream>>>(deg, bsum, off, M);

    // pass B: atomic-free scatter
    fill_sorted_kernel<<<(E + 255) / 256, 256, 0, stream>>>(row, col, off, rank, rs, E);

    prep_weights<<<256, 256, 0, stream>>>(W1, W2, wt1h, wt1l, wt2h, wt2l);
    to_bf16_scaled_kernel<<<(M * 16 + 255) / 256, 256, 0, stream>>>(x, dinv, xb, M * 16);

    // layer 1: gather pre-scaled x, then bf16-A MFMA GEMM 128->256 (+bias+gelu)
    gather_sum_kernel<false, true><<<(M * 64 + 255) / 256, 256, 0, stream>>>(
        off, deg, rs, dinv, dginv, xb, x, nullptr, nullptr, aggxb, M);
    gemm_bfA<128, 256, 1, 4, true, false, true, false><<<(M + 31) / 32, 256, 0, stream>>>(
        aggxb, wt1h, wt1l, b1, nullptr, nullptr, hb, M);

    // layer 2: MFMA GEMM 256->128 (fp32 + dinv-scaled bf16), then gather
    gemm_bfA<256, 128, 2, 2, false, true, true, true><<<(M + 63) / 64, 256, 0, stream>>>(
        hb, wt2h, wt2l, nullptr, dinv, xw2, xw2b, M);
    gather_sum_kernel<true, false><<<(M * 64 + 255) / 256, 256, 0, stream>>>(
        off, deg, rs, dinv, dginv, xw2b, xw2, b2, outw, nullptr, M);
}

// Round 11
// 365.107 us; speedup vs baseline: 19.0550x; 1.1289x over previous
//
#include <hip/hip_runtime.h>
#include <hip/hip_bf16.h>
#include <math.h>

typedef __attribute__((ext_vector_type(8))) short bf16x8;
typedef __attribute__((ext_vector_type(4))) float f32x4;

__device__ inline ushort f2bf(float f) {
    uint u = __float_as_uint(f);
    uint r = u + 0x7fffu + ((u >> 16) & 1u);
    return (ushort)(r >> 16);
}
__device__ inline float bf2f(ushort h) { return __uint_as_float(((uint)h) << 16); }

__device__ inline float gelu_tanh(float x) {
    float x3 = x * x * x;
    return 0.5f * x * (1.0f + tanhf(0.7978845608028654f * (x + 0.044715f * x3)));
}

// ---------------- pass A: degree histogram + per-edge rank ----------------

__global__ void deg_rank_kernel(const int* __restrict__ col, int* __restrict__ deg,
                                int* __restrict__ rank, int E) {
    int e = blockIdx.x * blockDim.x + threadIdx.x;
    if (e < E) rank[e] = atomicAdd(&deg[col[e]], 1);
}

__global__ void dinv_kernel(const int* __restrict__ deg, float* __restrict__ dinv, int M) {
    int i = blockIdx.x * blockDim.x + threadIdx.x;
    if (i < M) dinv[i] = rsqrtf((float)deg[i] + 1.0f);   // +1 self loop
}

// ---------------- hierarchical exclusive scan of deg -> off ----------------

__global__ void block_reduce_kernel(const int* __restrict__ deg, int* __restrict__ bsum, int M) {
    __shared__ int s[256];
    int i = blockIdx.x * 256 + threadIdx.x;
    s[threadIdx.x] = (i < M) ? deg[i] : 0;
    __syncthreads();
    for (int o = 128; o > 0; o >>= 1) {
        if (threadIdx.x < o) s[threadIdx.x] += s[threadIdx.x + o];
        __syncthreads();
    }
    if (threadIdx.x == 0) bsum[blockIdx.x] = s[0];
}

__global__ void scan_bsum_kernel(int* __restrict__ bsum, int nb) {
    __shared__ int s[512];
    int t = threadIdx.x;
    int orig = (t < nb) ? bsum[t] : 0;
    s[t] = orig;
    __syncthreads();
    for (int o = 1; o < 512; o <<= 1) {
        int v = 0;
        if (t >= o) v = s[t - o];
        __syncthreads();
        if (t >= o) s[t] += v;
        __syncthreads();
    }
    if (t < nb) bsum[t] = s[t] - orig;  // exclusive
}

__global__ void scan_offsets_kernel(const int* __restrict__ deg, const int* __restrict__ bsum,
                                    int* __restrict__ off, int M) {
    __shared__ int s[256];
    int i = blockIdx.x * 256 + threadIdx.x;
    int orig = (i < M) ? deg[i] : 0;
    s[threadIdx.x] = orig;
    __syncthreads();
    for (int o = 1; o < 256; o <<= 1) {
        int v = 0;
        if (threadIdx.x >= o) v = s[threadIdx.x - o];
        __syncthreads();
        if (threadIdx.x >= o) s[threadIdx.x] += v;
        __syncthreads();
    }
    if (i < M) off[i] = bsum[blockIdx.x] + s[threadIdx.x] - orig;  // exclusive
}

// ---------------- pass B: atomic-free CSR scatter ----------------

__global__ void fill_sorted_kernel(const int* __restrict__ row, const int* __restrict__ col,
                                   const int* __restrict__ off, const int* __restrict__ rank,
                                   int* __restrict__ rs, int E) {
    int e = blockIdx.x * blockDim.x + threadIdx.x;
    if (e < E) rs[off[col[e]] + rank[e]] = row[e];
}

// ---------------- weight prep: transpose + bf16 hi/lo split ----------------

__global__ void prep_weights(const float* __restrict__ W1, const float* __restrict__ W2,
                             ushort* __restrict__ wt1h, ushort* __restrict__ wt1l,
                             ushort* __restrict__ wt2h, ushort* __restrict__ wt2l) {
    int idx = blockIdx.x * 256 + threadIdx.x;
    if (idx < 128 * 256) {
        int k = idx >> 8, n = idx & 255;
        float f = W1[idx];
        ushort h = f2bf(f);
        wt1h[n * 128 + k] = h;
        wt1l[n * 128 + k] = f2bf(f - bf2f(h));
    } else if (idx < 2 * 128 * 256) {
        int i2 = idx - 128 * 256;
        int k = i2 >> 7, n = i2 & 127;
        float f = W2[i2];
        ushort h = f2bf(f);
        wt2h[n * 256 + k] = h;
        wt2l[n * 256 + k] = f2bf(f - bf2f(h));
    }
}

// ---------------- x -> bf16 table scaled by dinv[node] (8 elems/thread) ----------------

__global__ void to_bf16_scaled_kernel(const float* __restrict__ in, const float* __restrict__ dinv,
                                      ushort* __restrict__ out, int n8) {
    int i = blockIdx.x * 256 + threadIdx.x;
    if (i >= n8) return;
    float s = dinv[i >> 4];               // 16 chunks of 8 per 128-wide row
    float4 a = *(const float4*)(in + (size_t)i * 8);
    float4 b = *(const float4*)(in + (size_t)i * 8 + 4);
    ushort4 u0 = make_ushort4(f2bf(a.x * s), f2bf(a.y * s), f2bf(a.z * s), f2bf(a.w * s));
    ushort4 u1 = make_ushort4(f2bf(b.x * s), f2bf(b.y * s), f2bf(b.z * s), f2bf(b.w * s));
    *(ushort4*)(out + (size_t)i * 8) = u0;
    *(ushort4*)(out + (size_t)i * 8 + 4) = u1;
}

// ---------------- fused MLP: xw2b = dinv * (gelu(aggxb@W1 + b1) @ W2) ----------------
// Per block: 32 rows. Stage aggxb bf16 tile -> gemm1 (4 waves x 64 cols, W1
// hi/lo split) -> gelu+b1 -> bf16 h tile in LDS -> gemm2 (4 waves x 32 cols,
// K=256) -> write dinv-scaled bf16, IN PLACE over aggxb (same-row in/out).

__global__ __launch_bounds__(256) void gemm_fused(const ushort* __restrict__ A,
                                                  const ushort* __restrict__ wt1h,
                                                  const ushort* __restrict__ wt1l,
                                                  const float* __restrict__ b1,
                                                  const ushort* __restrict__ wt2h,
                                                  const ushort* __restrict__ wt2l,
                                                  const float* __restrict__ dinv,
                                                  ushort* __restrict__ Cb, int M) {
    __shared__ ushort la[32 * 128];   // aggx tile
    __shared__ ushort lh[32 * 256];   // h tile

    const int t = threadIdx.x;
    const int R0 = blockIdx.x * 32;

    // stage A tile (32x128 bf16), row-XOR swizzled
    #pragma unroll
    for (int base = 0; base < 512; base += 256) {
        int idx = base + t;
        int r = idx >> 4;             // /16 chunks per row
        int c8 = idx & 15;
        int gr = R0 + r;
        bf16x8 v = {};
        if (gr < M) v = *(const bf16x8*)(A + (size_t)gr * 128 + c8 * 8);
        int byte = (r * 128 + c8 * 8) * 2;
        byte ^= (r & 7) << 4;
        *(bf16x8*)((char*)la + byte) = v;
    }
    __syncthreads();

    const int w = t >> 6, l = t & 63;
    const int lrow = l & 15;
    const int lk = l >> 4;

    // ---- gemm1: rows 0..31, cols w*64..w*64+63, K=128 ----
    {
        const int c0w = w * 64;
        f32x4 acc[2][4] = {};
        #pragma unroll
        for (int ks = 0; ks < 4; ++ks) {
            const int kb = ks * 32 + lk * 8;
            bf16x8 a[2], bh[4], bl[4];
            #pragma unroll
            for (int m = 0; m < 2; ++m) {
                int lr = m * 16 + lrow;
                int byte = (lr * 128 + kb) * 2;
                byte ^= (lr & 7) << 4;
                a[m] = *(const bf16x8*)((const char*)la + byte);
            }
            #pragma unroll
            for (int n = 0; n < 4; ++n) {
                int col = c0w + n * 16 + lrow;
                bh[n] = *(const bf16x8*)&wt1h[(size_t)col * 128 + kb];
                bl[n] = *(const bf16x8*)&wt1l[(size_t)col * 128 + kb];
            }
            #pragma unroll
            for (int m = 0; m < 2; ++m)
                #pragma unroll
                for (int n = 0; n < 4; ++n) {
                    acc[m][n] = __builtin_amdgcn_mfma_f32_16x16x32_bf16(a[m], bh[n], acc[m][n], 0, 0, 0);
                    acc[m][n] = __builtin_amdgcn_mfma_f32_16x16x32_bf16(a[m], bl[n], acc[m][n], 0, 0, 0);
                }
        }
        // epilogue1: gelu(v + b1) -> bf16 h tile (swizzled ushort stores)
        #pragma unroll
        for (int m = 0; m < 2; ++m) {
            #pragma unroll
            for (int n = 0; n < 4; ++n) {
                int col = c0w + n * 16 + lrow;
                float bb = b1[col];
                #pragma unroll
                for (int reg = 0; reg < 4; ++reg) {
                    int rl = m * 16 + lk * 4 + reg;
                    float v = gelu_tanh(acc[m][n][reg] + bb);
                    int byte = (rl * 256 + col) * 2;
                    byte ^= (rl & 7) << 4;
                    *(ushort*)((char*)lh + byte) = f2bf(v);
                }
            }
        }
    }
    __syncthreads();

    // ---- gemm2: rows 0..31, cols w*32..w*32+31, K=256 ----
    {
        const int c0w = w * 32;
        f32x4 acc2[2][2] = {};
        #pragma unroll
        for (int ks = 0; ks < 8; ++ks) {
            const int kb = ks * 32 + lk * 8;
            bf16x8 a[2], bh[2], bl[2];
            #pragma unroll
            for (int m = 0; m < 2; ++m) {
                int lr = m * 16 + lrow;
                int byte = (lr * 256 + kb) * 2;
                byte ^= (lr & 7) << 4;
                a[m] = *(const bf16x8*)((const char*)lh + byte);
            }
            #pragma unroll
            for (int n = 0; n < 2; ++n) {
                int col = c0w + n * 16 + lrow;
                bh[n] = *(const bf16x8*)&wt2h[(size_t)col * 256 + kb];
                bl[n] = *(const bf16x8*)&wt2l[(size_t)col * 256 + kb];
            }
            #pragma unroll
            for (int m = 0; m < 2; ++m)
                #pragma unroll
                for (int n = 0; n < 2; ++n) {
                    acc2[m][n] = __builtin_amdgcn_mfma_f32_16x16x32_bf16(a[m], bh[n], acc2[m][n], 0, 0, 0);
                    acc2[m][n] = __builtin_amdgcn_mfma_f32_16x16x32_bf16(a[m], bl[n], acc2[m][n], 0, 0, 0);
                }
        }
        // epilogue2: write dinv-scaled bf16 (in place over aggxb rows)
        #pragma unroll
        for (int m = 0; m < 2; ++m) {
            #pragma unroll
            for (int reg = 0; reg < 4; ++reg) {
                int grow = R0 + m * 16 + lk * 4 + reg;
                if (grow < M) {
                    float sc = dinv[grow];
                    #pragma unroll
                    for (int n = 0; n < 2; ++n) {
                        int col = c0w + n * 16 + lrow;
                        Cb[(size_t)grow * 128 + col] = f2bf(acc2[m][n][reg] * sc);
                    }
                }
            }
        }
    }
}

// ---------------- segment-sum gather over pre-scaled bf16 table, F=128 ----------------
// One wave per node; 4 groups of 16 lanes, one edge per group. Self row comes
// from the SAME scaled table: out = dinv[i] * (sum_edges + self) (+bias).

template <bool BIAS, bool OUTBF>
__global__ __launch_bounds__(256) void gather_sum_kernel(const int* __restrict__ off,
                                                         const int* __restrict__ deg,
                                                         const int* __restrict__ rs,
                                                         const float* __restrict__ dinv,
                                                         const ushort* __restrict__ srcb,
                                                         const float* __restrict__ b,
                                                         float* __restrict__ dstf,
                                                         ushort* __restrict__ dstb, int M) {
    int wid = (blockIdx.x * 256 + threadIdx.x) >> 6;
    int lane = threadIdx.x & 63;
    int grp = lane >> 4;      // 0..3: which edge of the quad
    int l16 = lane & 15;      // feature block: 8 bf16 = 16B
    if (wid >= M) return;
    int s0 = off[wid];
    int n = deg[wid];
    float acc[8] = {};

    // self row (group 0 only, counts once)
    if (grp == 0) {
        bf16x8 u = *(const bf16x8*)(srcb + (size_t)wid * 128 + l16 * 8);
        #pragma unroll
        for (int i = 0; i < 8; ++i) acc[i] += bf2f((ushort)u[i]);
    }

    int j = 0;
    for (; j + 4 <= n; j += 4) {
        int r = rs[s0 + j + grp];
        bf16x8 u = *(const bf16x8*)(srcb + (size_t)r * 128 + l16 * 8);
        #pragma unroll
        for (int i = 0; i < 8; ++i) acc[i] += bf2f((ushort)u[i]);
    }
    if (j + grp < n) {
        int r = rs[s0 + j + grp];
        bf16x8 u = *(const bf16x8*)(srcb + (size_t)r * 128 + l16 * 8);
        #pragma unroll
        for (int i = 0; i < 8; ++i) acc[i] += bf2f((ushort)u[i]);
    }

    #pragma unroll
    for (int i = 0; i < 8; ++i) {
        acc[i] += __shfl_xor(acc[i], 16);
        acc[i] += __shfl_xor(acc[i], 32);
    }

    if (grp == 0) {
        float sc = dinv[wid];
        #pragma unroll
        for (int i = 0; i < 8; ++i) acc[i] *= sc;
        if constexpr (BIAS) {
            float4 b0 = *(const float4*)(b + l16 * 8);
            float4 b1 = *(const float4*)(b + l16 * 8 + 4);
            acc[0] += b0.x; acc[1] += b0.y; acc[2] += b0.z; acc[3] += b0.w;
            acc[4] += b1.x; acc[5] += b1.y; acc[6] += b1.z; acc[7] += b1.w;
        }
        if constexpr (OUTBF) {
            bf16x8 o;
            #pragma unroll
            for (int i = 0; i < 8; ++i) o[i] = (short)f2bf(acc[i]);
            *(bf16x8*)(dstb + (size_t)wid * 128 + l16 * 8) = o;
        } else {
            float4 o0 = make_float4(acc[0], acc[1], acc[2], acc[3]);
            float4 o1 = make_float4(acc[4], acc[5], acc[6], acc[7]);
            *(float4*)(dstf + (size_t)wid * 128 + l16 * 8) = o0;
            *(float4*)(dstf + (size_t)wid * 128 + l16 * 8 + 4) = o1;
        }
    }
}

// ---------------- launch ----------------

extern "C" void kernel_launch(void* const* d_in, const int* in_sizes, int n_in,
                              void* d_out, int out_size, void* d_ws, size_t ws_size,
                              hipStream_t stream) {
    const float* x  = (const float*)d_in[0];
    const int*   ei = (const int*)d_in[1];
    const float* W1 = (const float*)d_in[2];
    const float* b1 = (const float*)d_in[3];
    const float* W2 = (const float*)d_in[4];
    const float* b2 = (const float*)d_in[5];

    const int M = in_sizes[0] / 128;      // 100000
    const int E = in_sizes[1] / 2;        // 1600000
    const int* row = ei;
    const int* col = ei + E;

    // High-water ~66 MB.
    ushort* xb    = (ushort*)d_ws;              // 12,800,000 us (x*dinv, bf16)
    ushort* aggxb = xb + 12800000;              // 12,800,000 us [N,128]
    ushort* xw2b  = aggxb;                      // IN-PLACE alias (fused gemm same-row)
    float*  dinv  = (float*)(aggxb + 12800000); // 102,400 f
    int*    deg   = (int*)(dinv + 102400);      // 102,400 i  (memset full padded span!)
    int*    off   = deg + 102400;               // 102,400 i
    int*    rank  = off + 102400;               // 1,600,000 i
    int*    rs    = rank + 1600000;             // 1,600,000 i
    int*    bsum  = rs + 1600000;               // 1,024 i
    ushort* wt1h  = (ushort*)(bsum + 1024);     // 32,768 us each
    ushort* wt1l  = wt1h + 32768;
    ushort* wt2h  = wt1l + 32768;
    ushort* wt2l  = wt2h + 32768;
    float*  outw  = (float*)d_out;

    const int nb = (M + 255) / 256;

    hipMemsetAsync(deg, 0, (size_t)102400 * sizeof(int), stream);  // full padded span

    deg_rank_kernel<<<(E + 255) / 256, 256, 0, stream>>>(col, deg, rank, E);
    dinv_kernel<<<(M + 255) / 256, 256, 0, stream>>>(deg, dinv, M);

    block_reduce_kernel<<<nb, 256, 0, stream>>>(deg, bsum, M);
    scan_bsum_kernel<<<1, 512, 0, stream>>>(bsum, nb);
    scan_offsets_kernel<<<nb, 256, 0, stream>>>(deg, bsum, off, M);

    fill_sorted_kernel<<<(E + 255) / 256, 256, 0, stream>>>(row, col, off, rank, rs, E);

    prep_weights<<<256, 256, 0, stream>>>(W1, W2, wt1h, wt1l, wt2h, wt2l);
    to_bf16_scaled_kernel<<<(M * 16 + 255) / 256, 256, 0, stream>>>(x, dinv, xb, M * 16);

    // layer 1 aggregate (self from table), bf16 out
    gather_sum_kernel<false, true><<<(M * 64 + 255) / 256, 256, 0, stream>>>(
        off, deg, rs, dinv, xb, nullptr, nullptr, aggxb, M);

    // fused MLP: aggxb -> (gemm1+gelu+gemm2) -> dinv-scaled bf16 xw2b (in place)
    gemm_fused<<<(M + 31) / 32, 256, 0, stream>>>(aggxb, wt1h, wt1l, b1,
                                                  wt2h, wt2l, dinv, xw2b, M);

    // layer 2 aggregate (self from table) + bias, fp32 out
    gather_sum_kernel<true, false><<<(M * 64 + 255) / 256, 256, 0, stream>>>(
        off, deg, rs, dinv, xw2b, b2, outw, nullptr, M);
}